// Round 9
// baseline (2890.316 us; speedup 1.0000x reference)
//
#include <hip/hip_runtime.h>
#include <utility>

// ---------------- constants ----------------
#define BATCH   2
#define NT      16385          // tokens incl cls
#define NP      16640          // nystrom-padded length (65*256)
#define PADT    255            // front padding
#define LM      256            // landmarks
#define LAVG    65             // tokens averaged per landmark
#define NHEADS  8
#define DH      64
#define DIM     512
#define INDIM   1536
#define BH      (BATCH*NHEADS)
#define LNEPS   1e-5f
#define QSCALE  0.125f
#define MROWS   (BATCH*NT)     // 32770
#define MPAD    32896          // 257*128, padded rows for MFMA GEMMs
// flash split for attn3: NP = KS3 * KC3, KC3 multiple of 64
#define KS3     52
#define KC3     320            // 5 chunks of 64

typedef _Float16 f16x8_t __attribute__((ext_vector_type(8)));
typedef float    f32x4_t __attribute__((ext_vector_type(4)));

// split fp32 -> fp16 hi + fp16 lo (hi+lo carries ~22 mantissa bits)
__device__ __forceinline__ void split2(float f, unsigned short& hi, unsigned short& lo) {
    _Float16 h = (_Float16)f;
    float r = f - (float)h;
    _Float16 l = (_Float16)r;
    hi = __builtin_bit_cast(unsigned short, h);
    lo = __builtin_bit_cast(unsigned short, l);
}

__device__ __forceinline__ void async16(const unsigned short* g, unsigned short* l) {
    __builtin_amdgcn_global_load_lds((const __attribute__((address_space(1))) void*)g,
                                     (__attribute__((address_space(3))) void*)l, 16, 0, 0);
}

// ---------------- tiny kernels ----------------
__global__ void k_set_cls(const float* __restrict__ cls, float* __restrict__ h) {
    int i = blockIdx.x * 256 + threadIdx.x;
    if (i < BATCH * DIM) {
        int b = i / DIM, c = i % DIM;
        h[(size_t)b * NT * DIM + c] = cls[c];
    }
}

__global__ void k_copy_cls(const float* __restrict__ src, float* __restrict__ dst) {
    int i = blockIdx.x * 256 + threadIdx.x;
    if (i < BATCH * DIM) {
        int b = i / DIM, c = i % DIM;
        dst[(size_t)b * NT * DIM + c] = src[(size_t)b * NT * DIM + c];
    }
}

// zero pads of q,k,v fp32 AND the q/k split-fp16 buffers (attn3 reads K pads)
__global__ void k_zero_pads(float* __restrict__ q, float* __restrict__ k, float* __restrict__ v,
                            unsigned short* __restrict__ qsh, unsigned short* __restrict__ qsl,
                            unsigned short* __restrict__ ksh, unsigned short* __restrict__ ksl) {
    int idx = blockIdx.x * 256 + threadIdx.x;
    const int per = PADT * DH;
    if (idx < BH * per) {
        int bh = idx / per, rest = idx % per;
        size_t off = (size_t)bh * NP * DH + rest;
        q[off] = 0.f; k[off] = 0.f; v[off] = 0.f;
        qsh[off] = 0; qsl[off] = 0; ksh[off] = 0; ksl[off] = 0;
    }
}

// fp32 -> (hi,lo) fp16 pair, vectorized by 4
__global__ void k_cvt_split(const float* __restrict__ x, unsigned short* __restrict__ yh,
                            unsigned short* __restrict__ yl, int n4) {
    int i = blockIdx.x * 256 + threadIdx.x;
    if (i < n4) {
        float4 v = ((const float4*)x)[i];
        ushort4 oh, ol;
        split2(v.x, oh.x, ol.x); split2(v.y, oh.y, ol.y);
        split2(v.z, oh.z, ol.z); split2(v.w, oh.w, ol.w);
        ((ushort4*)yh)[i] = oh;
        ((ushort4*)yl)[i] = ol;
    }
}

// W [K][N] fp32 -> Wt [N][K] fp16 hi/lo
__global__ void k_wt_split(const float* __restrict__ W, unsigned short* __restrict__ Wth,
                           unsigned short* __restrict__ Wtl, int K, int N) {
    int idx = blockIdx.x * 256 + threadIdx.x;
    if (idx < K * N) {
        int k = idx / N, n = idx % N;
        unsigned short h, l;
        split2(W[idx], h, l);
        Wth[(size_t)n * K + k] = h;
        Wtl[(size_t)n * K + k] = l;
    }
}

// ---------------- split-fp16 MFMA GEMM core: 128x128 tile, BK=32 ----------------
__device__ __forceinline__ void mfma_core_s(
        const unsigned short* __restrict__ Ah, const unsigned short* __restrict__ Al,
        const unsigned short* __restrict__ Bh, const unsigned short* __restrict__ Bl,
        int K, int m0, int n0,
        unsigned short* lAh, unsigned short* lAl,
        unsigned short* lBh, unsigned short* lBl, f32x4_t acc[4][4]) {
    const int tid = threadIdx.x;
    const int lane = tid & 63, wave = tid >> 6;
    const int wm = (wave >> 1) * 64, wn = (wave & 1) * 64;
    const int mrow = lane & 15, kg = lane >> 4;
    const int arow = tid >> 2, acol = (tid & 3) * 8;
    for (int k0 = 0; k0 < K; k0 += 32) {
        size_t aoff  = (size_t)(m0 + arow) * K + k0 + acol;
        size_t aoff2 = aoff + (size_t)64 * K;
        size_t boff  = (size_t)(n0 + arow) * K + k0 + acol;
        size_t boff2 = boff + (size_t)64 * K;
        async16(Ah + aoff,  lAh + tid * 8);
        async16(Ah + aoff2, lAh + 2048 + tid * 8);
        async16(Al + aoff,  lAl + tid * 8);
        async16(Al + aoff2, lAl + 2048 + tid * 8);
        async16(Bh + boff,  lBh + tid * 8);
        async16(Bh + boff2, lBh + 2048 + tid * 8);
        async16(Bl + boff,  lBl + tid * 8);
        async16(Bl + boff2, lBl + 2048 + tid * 8);
        __syncthreads();
        f16x8_t ah[4], al[4], bh[4], bl[4];
#pragma unroll
        for (int i = 0; i < 4; i++) {
            int ro = (wm + i * 16 + mrow) * 32 + kg * 8;
            ah[i] = *(const f16x8_t*)(lAh + ro);
            al[i] = *(const f16x8_t*)(lAl + ro);
        }
#pragma unroll
        for (int j = 0; j < 4; j++) {
            int ro = (wn + j * 16 + mrow) * 32 + kg * 8;
            bh[j] = *(const f16x8_t*)(lBh + ro);
            bl[j] = *(const f16x8_t*)(lBl + ro);
        }
#pragma unroll
        for (int i = 0; i < 4; i++)
#pragma unroll
            for (int j = 0; j < 4; j++) {
                acc[i][j] = __builtin_amdgcn_mfma_f32_16x16x32_f16(ah[i], bh[j], acc[i][j], 0, 0, 0);
                acc[i][j] = __builtin_amdgcn_mfma_f32_16x16x32_f16(al[i], bh[j], acc[i][j], 0, 0, 0);
                acc[i][j] = __builtin_amdgcn_mfma_f32_16x16x32_f16(ah[i], bl[j], acc[i][j], 0, 0, 0);
            }
        __syncthreads();
    }
}

#define MFMA_LDS \
    __shared__ __align__(16) unsigned short lAh[4096]; \
    __shared__ __align__(16) unsigned short lAl[4096]; \
    __shared__ __align__(16) unsigned short lBh[4096]; \
    __shared__ __align__(16) unsigned short lBl[4096];

// w1: relu(feat @ W1t + b1) -> h1 (with cls row offset). M=32768, K=1536, N=512
// grid (m-tiles=256, n-tiles=4): m fast -> A fetched once, B L2-resident
__global__ __launch_bounds__(256) void k_w1_s(
        const unsigned short* __restrict__ Ah, const unsigned short* __restrict__ Al,
        const unsigned short* __restrict__ Bh, const unsigned short* __restrict__ Bl,
        const float* __restrict__ bias, float* __restrict__ hout) {
    MFMA_LDS
    f32x4_t acc[4][4] = {};
    int m0 = blockIdx.x * 128, n0 = blockIdx.y * 128;
    mfma_core_s(Ah, Al, Bh, Bl, INDIM, m0, n0, lAh, lAl, lBh, lBl, acc);
    int lane = threadIdx.x & 63, wave = threadIdx.x >> 6;
    int wm = (wave >> 1) * 64, wn = (wave & 1) * 64;
    int c16 = lane & 15, kg = lane >> 4;
#pragma unroll
    for (int i = 0; i < 4; i++)
#pragma unroll
        for (int r = 0; r < 4; r++) {
            int row = m0 + wm + i * 16 + kg * 4 + r;
            int b = row >> 14;
            size_t orow = (size_t)row + b + 1;
#pragma unroll
            for (int j = 0; j < 4; j++) {
                int col = n0 + wn + j * 16 + c16;
                float v = acc[i][j][r] + bias[col];
                hout[orow * DIM + col] = fmaxf(v, 0.f);
            }
        }
}

// qkv: act @ Wqkvt -> scatter q,k,v (fp32) + fused split-fp16 for q,k.
// M=32770(pad 32896), K=512, N=1536. grid (m-tiles=257, n-tiles=12)
__global__ __launch_bounds__(256) void k_qkv_s(
        const unsigned short* __restrict__ Ah, const unsigned short* __restrict__ Al,
        const unsigned short* __restrict__ Bh, const unsigned short* __restrict__ Bl,
        float* __restrict__ q, float* __restrict__ k, float* __restrict__ v,
        unsigned short* __restrict__ qsh, unsigned short* __restrict__ qsl,
        unsigned short* __restrict__ ksh, unsigned short* __restrict__ ksl) {
    MFMA_LDS
    f32x4_t acc[4][4] = {};
    int m0 = blockIdx.x * 128, n0 = blockIdx.y * 128;
    mfma_core_s(Ah, Al, Bh, Bl, DIM, m0, n0, lAh, lAl, lBh, lBl, acc);
    int lane = threadIdx.x & 63, wave = threadIdx.x >> 6;
    int wm = (wave >> 1) * 64, wn = (wave & 1) * 64;
    int c16 = lane & 15, kg = lane >> 4;
#pragma unroll
    for (int i = 0; i < 4; i++)
#pragma unroll
        for (int r = 0; r < 4; r++) {
            int row = m0 + wm + i * 16 + kg * 4 + r;
            if (row >= MROWS) continue;
            int b = row / NT, tok = row % NT;
            size_t t = (size_t)tok + PADT;
#pragma unroll
            for (int j = 0; j < 4; j++) {
                int col = n0 + wn + j * 16 + c16;
                int sel = col >> 9, hh = (col >> 6) & 7, d = col & 63;
                float vv = acc[i][j][r];
                size_t off = ((size_t)(b * NHEADS + hh) * NP + t) * DH + d;
                if (sel == 0) {
                    vv *= QSCALE;
                    q[off] = vv;
                    unsigned short h, l; split2(vv, h, l);
                    qsh[off] = h; qsl[off] = l;
                } else if (sel == 1) {
                    k[off] = vv;
                    unsigned short h, l; split2(vv, h, l);
                    ksh[off] = h; ksl[off] = l;
                } else {
                    v[off] = vv;
                }
            }
        }
}

// outproj: hio += act @ Woutt + bias. M=32770(pad), K=512, N=512. grid (257, 4)
__global__ __launch_bounds__(256) void k_outproj_s(
        const unsigned short* __restrict__ Ah, const unsigned short* __restrict__ Al,
        const unsigned short* __restrict__ Bh, const unsigned short* __restrict__ Bl,
        const float* __restrict__ bias, float* __restrict__ hio) {
    MFMA_LDS
    f32x4_t acc[4][4] = {};
    int m0 = blockIdx.x * 128, n0 = blockIdx.y * 128;
    mfma_core_s(Ah, Al, Bh, Bl, DIM, m0, n0, lAh, lAl, lBh, lBl, acc);
    int lane = threadIdx.x & 63, wave = threadIdx.x >> 6;
    int wm = (wave >> 1) * 64, wn = (wave & 1) * 64;
    int c16 = lane & 15, kg = lane >> 4;
#pragma unroll
    for (int i = 0; i < 4; i++)
#pragma unroll
        for (int r = 0; r < 4; r++) {
            int row = m0 + wm + i * 16 + kg * 4 + r;
            if (row >= MROWS) continue;
#pragma unroll
            for (int j = 0; j < 4; j++) {
                int col = n0 + wn + j * 16 + c16;
                hio[(size_t)row * DIM + col] += acc[i][j][r] + bias[col];
            }
        }
}

// ---------------- layernorm -> split fp16 ----------------
__global__ __launch_bounds__(256) void k_ln_split(
        const float* __restrict__ x, const float* __restrict__ g,
        const float* __restrict__ bb, unsigned short* __restrict__ yh,
        unsigned short* __restrict__ yl) {
    size_t row = blockIdx.x;
    const float* xr = x + row * DIM;
    int tid = threadIdx.x;
    __shared__ float red[256];
    float v0 = xr[tid], v1 = xr[tid + 256];
    red[tid] = v0 + v1;
    __syncthreads();
    for (int o = 128; o > 0; o >>= 1) { if (tid < o) red[tid] += red[tid + o]; __syncthreads(); }
    float mu = red[0] * (1.0f / DIM);
    __syncthreads();
    float d0 = v0 - mu, d1 = v1 - mu;
    red[tid] = d0 * d0 + d1 * d1;
    __syncthreads();
    for (int o = 128; o > 0; o >>= 1) { if (tid < o) red[tid] += red[tid + o]; __syncthreads(); }
    float rs = rsqrtf(red[0] * (1.0f / DIM) + LNEPS);
    float y0 = d0 * rs * g[tid] + bb[tid];
    float y1 = d1 * rs * g[tid + 256] + bb[tid + 256];
    unsigned short h, l;
    split2(y0, h, l);
    yh[row * DIM + tid] = h; yl[row * DIM + tid] = l;
    split2(y1, h, l);
    yh[row * DIM + tid + 256] = h; yl[row * DIM + tid + 256] = l;
}

// ---------------- landmarks (fp32 + split fp16 outputs) ----------------
__global__ void k_landmark(const float* __restrict__ x, float* __restrict__ xl,
                           unsigned short* __restrict__ xsh, unsigned short* __restrict__ xsl) {
    int bh = blockIdx.z, i = blockIdx.y, d = threadIdx.x;
    const float* p = x + ((size_t)bh * NP + (size_t)i * LAVG) * DH + d;
    float s = 0.f;
    for (int j = 0; j < LAVG; j++) s += p[(size_t)j * DH];
    float v = s * (1.0f / LAVG);
    size_t o = ((size_t)bh * LM + i) * DH + d;
    xl[o] = v;
    unsigned short h, l; split2(v, h, l);
    xsh[o] = h; xsl[o] = l;
}

// ---------------- V [bh][NP][64] fp32 -> Vt split [bh][64][NP] ----------------
__global__ __launch_bounds__(256) void k_vt_split(
        const float* __restrict__ V, unsigned short* __restrict__ Yh,
        unsigned short* __restrict__ Yl) {
    int t0 = blockIdx.x * 64, bh = blockIdx.y;
    __shared__ float tile[64][65];
    int tid = threadIdx.x;
#pragma unroll
    for (int u = 0; u < 4; u++) {
        int idx = tid + u * 256;
        int row = idx >> 4, c4 = (idx & 15) * 4;
        *(float4*)&tile[row][c4] = *(const float4*)(V + ((size_t)bh * NP + t0 + row) * DH + c4);
    }
    __syncthreads();
    int d = tid >> 2, g16 = (tid & 3) * 16;
    __attribute__((aligned(16))) unsigned short oh[16], ol[16];
#pragma unroll
    for (int u = 0; u < 16; u++) split2(tile[g16 + u][d], oh[u], ol[u]);
    size_t o = ((size_t)bh * DH + d) * NP + t0 + g16;
#pragma unroll
    for (int u = 0; u < 4; u++) {
        *(ushort4*)(Yh + o + u * 4) = *(const ushort4*)&oh[u * 4];
        *(ushort4*)(Yl + o + u * 4) = *(const ushort4*)&ol[u * 4];
    }
}

// ---------------- M2 [bh][256][64] fp32 -> M2t split [bh][64][256] ----------------
__global__ __launch_bounds__(256) void k_m2t_split(
        const float* __restrict__ M2, unsigned short* __restrict__ Yh,
        unsigned short* __restrict__ Yl) {
    int l0 = blockIdx.x * 64, bh = blockIdx.y;
    __shared__ float tile[64][65];
    int tid = threadIdx.x;
#pragma unroll
    for (int u = 0; u < 4; u++) {
        int idx = tid + u * 256;
        int row = idx >> 4, c4 = (idx & 15) * 4;
        *(float4*)&tile[row][c4] = *(const float4*)(M2 + ((size_t)bh * LM + l0 + row) * DH + c4);
    }
    __syncthreads();
    int d = tid >> 2, g16 = (tid & 3) * 16;
    __attribute__((aligned(16))) unsigned short oh[16], ol[16];
#pragma unroll
    for (int u = 0; u < 16; u++) split2(tile[g16 + u][d], oh[u], ol[u]);
    size_t o = ((size_t)bh * DH + d) * LM + l0 + g16;
#pragma unroll
    for (int u = 0; u < 4; u++) {
        *(ushort4*)(Yh + o + u * 4) = *(const ushort4*)&oh[u * 4];
        *(ushort4*)(Yl + o + u * 4) = *(const ushort4*)&ol[u * 4];
    }
}

// ---------------- scores (small, a2 only): C[bh,r,c] = A[bh,r,:]·B[bh,c,:] ----------------
__global__ __launch_bounds__(256) void k_scores(
        const float* __restrict__ A, const float* __restrict__ Bm,
        float* __restrict__ C, int Mrows, int Ncols) {
    int bh = blockIdx.z;
    int c0 = blockIdx.x * 64, r0 = blockIdx.y * 64;
    __shared__ float As[64][DH + 1];
    __shared__ float Bs[64][DH + 1];
    int tid = threadIdx.x;
    int tc = tid & 15, tr = tid >> 4;
#pragma unroll
    for (int rep = 0; rep < 4; rep++) {
        int row = rep * 16 + (tid >> 4);
        int c4 = (tid & 15) * 4;
        float4 va = *(const float4*)(A + ((size_t)bh * Mrows + r0 + row) * DH + c4);
        As[row][c4 + 0] = va.x; As[row][c4 + 1] = va.y; As[row][c4 + 2] = va.z; As[row][c4 + 3] = va.w;
        float4 vb = *(const float4*)(Bm + ((size_t)bh * Ncols + c0 + row) * DH + c4);
        Bs[row][c4 + 0] = vb.x; Bs[row][c4 + 1] = vb.y; Bs[row][c4 + 2] = vb.z; Bs[row][c4 + 3] = vb.w;
    }
    __syncthreads();
    float acc[4][4] = {};
#pragma unroll 8
    for (int kk = 0; kk < DH; kk++) {
        float a_[4], b_[4];
#pragma unroll
        for (int i = 0; i < 4; i++) a_[i] = As[tr * 4 + i][kk];
#pragma unroll
        for (int j = 0; j < 4; j++) b_[j] = Bs[tc * 4 + j][kk];
#pragma unroll
        for (int i = 0; i < 4; i++)
#pragma unroll
            for (int j = 0; j < 4; j++) acc[i][j] += a_[i] * b_[j];
    }
#pragma unroll
    for (int i = 0; i < 4; i++)
#pragma unroll
        for (int j = 0; j < 4; j++)
            C[((size_t)bh * Mrows + r0 + tr * 4 + i) * Ncols + c0 + tc * 4 + j] = acc[i][j];
}

// ---------------- row softmax, in place (small, a2 only) ----------------
__global__ __launch_bounds__(256) void k_softmax(float* __restrict__ S, int len) {
    size_t row = blockIdx.x;
    float* p = S + row * (size_t)len;
    int tid = threadIdx.x;
    __shared__ float red[256];
    float m = -1e30f;
    for (int i = tid; i < len; i += 256) m = fmaxf(m, p[i]);
    red[tid] = m;
    __syncthreads();
    for (int o = 128; o > 0; o >>= 1) { if (tid < o) red[tid] = fmaxf(red[tid], red[tid + o]); __syncthreads(); }
    m = red[0];
    __syncthreads();
    float s = 0.f;
    for (int i = tid; i < len; i += 256) s += __expf(p[i] - m);
    red[tid] = s;
    __syncthreads();
    for (int o = 128; o > 0; o >>= 1) { if (tid < o) red[tid] += red[tid + o]; __syncthreads(); }
    float inv = 1.0f / red[0];
    for (int i = tid; i < len; i += 256) p[i] = __expf(p[i] - m) * inv;
}

// ---------------- pinv scalars ----------------
__global__ __launch_bounds__(256) void k_pinv_scal(const float* __restrict__ a2, float* __restrict__ scal) {
    int bh = blockIdx.x, tid = threadIdx.x;
    const float* p = a2 + (size_t)bh * LM * LM;
    float cs = 0.f, rs = 0.f;
    for (int i = 0; i < LM; i++) cs += fabsf(p[(size_t)i * LM + tid]);
    for (int j = 0; j < LM; j++) rs += fabsf(p[(size_t)tid * LM + j]);
    __shared__ float red[256];
    red[tid] = rs;
    __syncthreads();
    for (int o = 128; o > 0; o >>= 1) { if (tid < o) red[tid] = fmaxf(red[tid], red[tid + o]); __syncthreads(); }
    if (tid == 0) atomicMax((int*)&scal[0], __float_as_int(red[0]));
    __syncthreads();
    red[tid] = cs;
    __syncthreads();
    for (int o = 128; o > 0; o >>= 1) { if (tid < o) red[tid] = fmaxf(red[tid], red[tid + o]); __syncthreads(); }
    if (tid == 0) atomicMax((int*)&scal[1], __float_as_int(red[0]));
}

__global__ void k_z0(const float* __restrict__ a2, const float* __restrict__ scal, float* __restrict__ z) {
    int bh = blockIdx.z, i = blockIdx.y, j = threadIdx.x;
    float inv = 1.0f / (scal[0] * scal[1]);
    z[((size_t)bh * LM + i) * LM + j] = a2[((size_t)bh * LM + j) * LM + i] * inv;
}

// ---------------- batched fp32 GEMM, 64x64 tile, BK=32, 4x4/thread ----------------
// C = alpha*(A@B) + beta*E + dval*I   (E optional, fp32 row-major same shape as C)
__global__ __launch_bounds__(256) void k_gemm_b64(
        const float* __restrict__ A, const float* __restrict__ Bm, float* __restrict__ C,
        const float* __restrict__ E, int Mr, int Nc, int Kd,
        float alpha, float beta, float dval) {
    int bh = blockIdx.z;
    int r0 = blockIdx.y * 64, c0 = blockIdx.x * 64;
    const float* Ab = A + (size_t)bh * Mr * Kd;
    const float* Bb = Bm + (size_t)bh * Kd * Nc;
    __shared__ float As[64][36];
    __shared__ float Bs[32][68];
    int tid = threadIdx.x;
    int tr = tid >> 4, tc = tid & 15;
    int arw = tid >> 2, ac8 = (tid & 3) * 8;
    int brw = tid >> 3, bc8 = (tid & 7) * 8;
    float acc[4][4] = {};
    for (int k0 = 0; k0 < Kd; k0 += 32) {
        float4 a0 = *(const float4*)(Ab + (size_t)(r0 + arw) * Kd + k0 + ac8);
        float4 a1 = *(const float4*)(Ab + (size_t)(r0 + arw) * Kd + k0 + ac8 + 4);
        *(float4*)&As[arw][ac8] = a0;
        *(float4*)&As[arw][ac8 + 4] = a1;
        float4 b0 = *(const float4*)(Bb + (size_t)(k0 + brw) * Nc + c0 + bc8);
        float4 b1 = *(const float4*)(Bb + (size_t)(k0 + brw) * Nc + c0 + bc8 + 4);
        *(float4*)&Bs[brw][bc8] = b0;
        *(float4*)&Bs[brw][bc8 + 4] = b1;
        __syncthreads();
#pragma unroll
        for (int kk = 0; kk < 32; kk++) {
            float a_[4], b_[4];
#pragma unroll
            for (int i = 0; i < 4; i++) a_[i] = As[tr * 4 + i][kk];
#pragma unroll
            for (int j = 0; j < 4; j++) b_[j] = Bs[kk][tc * 4 + j];
#pragma unroll
            for (int i = 0; i < 4; i++)
#pragma unroll
                for (int j = 0; j < 4; j++) acc[i][j] += a_[i] * b_[j];
        }
        __syncthreads();
    }
#pragma unroll
    for (int i = 0; i < 4; i++)
#pragma unroll
        for (int j = 0; j < 4; j++) {
            int r = r0 + tr * 4 + i, c = c0 + tc * 4 + j;
            float vv = alpha * acc[i][j] + ((r == c) ? dval : 0.f);
            if (E) vv += beta * E[(size_t)bh * Mr * Nc + (size_t)r * Nc + c];
            C[(size_t)bh * Mr * Nc + (size_t)r * Nc + c] = vv;
        }
}

// ================ MFMA fused attention ================
// Tile layout in LDS (split-fp16): [kstep s][row][32] ushort, off = (s*64+row)*32+kk.
// A/B fragment conventions identical to mfma_core_s (verified):
//   A frag: row = lane&15 (+ row-block), k-octet = (lane>>4)*8;  B same on Bt rows.
//   C/D: col = lane&15, row = (lane>>4)*4 + reg.
// Each wave owns output rows w*16..w*16+15 and iterates 4 col-fragments j.

// attn1: softmax(q @ kl^T) @ M2 -> attn_out.  grid (ceil(NT/64), BH)
__global__ __launch_bounds__(256, 2) void k_attn1_mfma(
        const unsigned short* __restrict__ qsh, const unsigned short* __restrict__ qsl,
        const unsigned short* __restrict__ klsh, const unsigned short* __restrict__ klsl,
        const unsigned short* __restrict__ m2h, const unsigned short* __restrict__ m2l,
        float* __restrict__ attn_out) {
    int tt = blockIdx.x, bh = blockIdx.y;
    int b = bh / NHEADS, hh = bh % NHEADS;
    int tok0 = tt * 64;
    __shared__ __align__(16) unsigned short lQh[4096], lQl[4096];
    __shared__ __align__(16) unsigned short lBh[4096], lBl[4096];
    __shared__ __align__(16) unsigned short lPh[4096], lPl[4096];
    __shared__ __align__(16) unsigned short lVh[4096], lVl[4096];
    int tid = threadIdx.x;
    int lane = tid & 63, w = tid >> 6;
    int mrow = lane & 15, kg = lane >> 4;
    int arow = tid >> 2, acol = (tid & 3) * 8;
    {   // stage q tile once (row-clamped per thread; clamped rows are dead)
        int tok = tok0 + arow; if (tok >= NT) tok = NT - 1;
        size_t src = ((size_t)bh * NP + tok + PADT) * DH + acol;
        async16(qsh + src,      lQh + tid * 8);
        async16(qsh + src + 32, lQh + 2048 + tid * 8);
        async16(qsl + src,      lQl + tid * 8);
        async16(qsl + src + 32, lQl + 2048 + tid * 8);
    }
    float m_[4], l_[4];
    f32x4_t oacc[4];
#pragma unroll
    for (int r = 0; r < 4; r++) { m_[r] = -1e30f; l_[r] = 0.f; }
#pragma unroll
    for (int j = 0; j < 4; j++) oacc[j] = (f32x4_t){0.f, 0.f, 0.f, 0.f};
    for (int ck = 0; ck < 4; ck++) {
        if (ck) __syncthreads();   // prev PV done with lP/lV; prev scores done with lB
        {
            size_t sb = ((size_t)bh * LM + ck * 64 + arow) * DH + acol;
            async16(klsh + sb,      lBh + tid * 8);
            async16(klsh + sb + 32, lBh + 2048 + tid * 8);
            async16(klsl + sb,      lBl + tid * 8);
            async16(klsl + sb + 32, lBl + 2048 + tid * 8);
            size_t sv = ((size_t)bh * DH + arow) * LM + ck * 64 + acol;
            async16(m2h + sv,      lVh + tid * 8);
            async16(m2h + sv + 32, lVh + 2048 + tid * 8);
            async16(m2l + sv,      lVl + tid * 8);
            async16(m2l + sv + 32, lVl + 2048 + tid * 8);
        }
        __syncthreads();   // stages visible (covers lQ on ck==0)
        f32x4_t acc1[4];
#pragma unroll
        for (int j = 0; j < 4; j++) acc1[j] = (f32x4_t){0.f, 0.f, 0.f, 0.f};
#pragma unroll
        for (int s = 0; s < 2; s++) {
            int ao = (s * 64 + w * 16 + mrow) * 32 + kg * 8;
            f16x8_t ah = *(const f16x8_t*)(lQh + ao);
            f16x8_t al = *(const f16x8_t*)(lQl + ao);
#pragma unroll
            for (int j = 0; j < 4; j++) {
                int bo = (s * 64 + j * 16 + mrow) * 32 + kg * 8;
                f16x8_t bhv = *(const f16x8_t*)(lBh + bo);
                f16x8_t blv = *(const f16x8_t*)(lBl + bo);
                acc1[j] = __builtin_amdgcn_mfma_f32_16x16x32_f16(ah, bhv, acc1[j], 0, 0, 0);
                acc1[j] = __builtin_amdgcn_mfma_f32_16x16x32_f16(al, bhv, acc1[j], 0, 0, 0);
                acc1[j] = __builtin_amdgcn_mfma_f32_16x16x32_f16(ah, blv, acc1[j], 0, 0, 0);
            }
        }
        // online softmax; each lane owns rows w*16+kg*4+r, cols j*16+mrow
#pragma unroll
        for (int r = 0; r < 4; r++) {
            float cm = fmaxf(fmaxf(acc1[0][r], acc1[1][r]), fmaxf(acc1[2][r], acc1[3][r]));
            cm = fmaxf(cm, __shfl_xor(cm, 1));
            cm = fmaxf(cm, __shfl_xor(cm, 2));
            cm = fmaxf(cm, __shfl_xor(cm, 4));
            cm = fmaxf(cm, __shfl_xor(cm, 8));
            float mn = fmaxf(m_[r], cm);
            float f = __expf(m_[r] - mn);
            float p0 = __expf(acc1[0][r] - mn);
            float p1 = __expf(acc1[1][r] - mn);
            float p2 = __expf(acc1[2][r] - mn);
            float p3 = __expf(acc1[3][r] - mn);
            float ps = p0 + p1 + p2 + p3;
            ps += __shfl_xor(ps, 1);
            ps += __shfl_xor(ps, 2);
            ps += __shfl_xor(ps, 4);
            ps += __shfl_xor(ps, 8);
            l_[r] = l_[r] * f + ps;
            m_[r] = mn;
#pragma unroll
            for (int j = 0; j < 4; j++) oacc[j][r] *= f;
            int row = w * 16 + kg * 4 + r;
            float pv[4] = {p0, p1, p2, p3};
#pragma unroll
            for (int j = 0; j < 4; j++) {
                unsigned short ph_, pl_;
                split2(pv[j], ph_, pl_);
                int col = j * 16 + mrow;
                int off = ((col >> 5) * 64 + row) * 32 + (col & 31);
                lPh[off] = ph_; lPl[off] = pl_;
            }
        }
        __syncthreads();   // P visible
#pragma unroll
        for (int s = 0; s < 2; s++) {
            int ao = (s * 64 + w * 16 + mrow) * 32 + kg * 8;
            f16x8_t ph = *(const f16x8_t*)(lPh + ao);
            f16x8_t pl = *(const f16x8_t*)(lPl + ao);
#pragma unroll
            for (int j = 0; j < 4; j++) {
                int bo = (s * 64 + j * 16 + mrow) * 32 + kg * 8;
                f16x8_t vh = *(const f16x8_t*)(lVh + bo);
                f16x8_t vl = *(const f16x8_t*)(lVl + bo);
                oacc[j] = __builtin_amdgcn_mfma_f32_16x16x32_f16(ph, vh, oacc[j], 0, 0, 0);
                oacc[j] = __builtin_amdgcn_mfma_f32_16x16x32_f16(pl, vh, oacc[j], 0, 0, 0);
                oacc[j] = __builtin_amdgcn_mfma_f32_16x16x32_f16(ph, vl, oacc[j], 0, 0, 0);
            }
        }
    }
#pragma unroll
    for (int r = 0; r < 4; r++) {
        int row = w * 16 + kg * 4 + r;
        int tok = tok0 + row;
        if (tok >= NT) continue;
        float inv = 1.0f / l_[r];
#pragma unroll
        for (int j = 0; j < 4; j++)
            attn_out[((size_t)b * NT + tok) * DIM + hh * DH + j * 16 + mrow] = oacc[j][r] * inv;
    }
}

// attn3: softmax(ql @ k^T) @ v with split-K over NP -> part + ml.  grid (KS3, LM/64, BH)
__global__ __launch_bounds__(256, 2) void k_attn3_mfma(
        const unsigned short* __restrict__ qlh, const unsigned short* __restrict__ qll,
        const unsigned short* __restrict__ kh, const unsigned short* __restrict__ kl_,
        const unsigned short* __restrict__ vth, const unsigned short* __restrict__ vtl,
        float* __restrict__ part, float* __restrict__ ml) {
    int ks = blockIdx.x, rt = blockIdx.y, bh = blockIdx.z;
    int r0 = rt * 64;
    __shared__ __align__(16) unsigned short lQh[4096], lQl[4096];
    __shared__ __align__(16) unsigned short lBh[4096], lBl[4096];
    __shared__ __align__(16) unsigned short lPh[4096], lPl[4096];
    __shared__ __align__(16) unsigned short lVh[4096], lVl[4096];
    int tid = threadIdx.x;
    int lane = tid & 63, w = tid >> 6;
    int mrow = lane & 15, kg = lane >> 4;
    int arow = tid >> 2, acol = (tid & 3) * 8;
    {   // stage ql tile once
        size_t src = ((size_t)bh * LM + r0 + arow) * DH + acol;
        async16(qlh + src,      lQh + tid * 8);
        async16(qlh + src + 32, lQh + 2048 + tid * 8);
        async16(qll + src,      lQl + tid * 8);
        async16(qll + src + 32, lQl + 2048 + tid * 8);
    }
    float m_[4], l_[4];
    f32x4_t oacc[4];
#pragma unroll
    for (int r = 0; r < 4; r++) { m_[r] = -1e30f; l_[r] = 0.f; }
#pragma unroll
    for (int j = 0; j < 4; j++) oacc[j] = (f32x4_t){0.f, 0.f, 0.f, 0.f};
    for (int t0 = ks * KC3; t0 < (ks + 1) * KC3; t0 += 64) {
        if (t0 != ks * KC3) __syncthreads();
        {
            size_t sb = ((size_t)bh * NP + t0 + arow) * DH + acol;
            async16(kh + sb,       lBh + tid * 8);
            async16(kh + sb + 32,  lBh + 2048 + tid * 8);
            async16(kl_ + sb,      lBl + tid * 8);
            async16(kl_ + sb + 32, lBl + 2048 + tid * 8);
            size_t sv = ((size_t)bh * DH + arow) * NP + t0 + acol;
            async16(vth + sv,      lVh + tid * 8);
            async16(vth + sv + 32, lVh + 2048 + tid * 8);
            async16(vtl + sv,      lVl + tid * 8);
            async16(vtl + sv + 32, lVl + 2048 + tid * 8);
        }
        __syncthreads();
        f32x4_t acc1[4];
#pragma unroll
        for (int j = 0; j < 4; j++) acc1[j] = (f32x4_t){0.f, 0.f, 0.f, 0.f};
#pragma unroll
        for (int s = 0; s < 2; s++) {
            int ao = (s * 64 + w * 16 + mrow) * 32 + kg * 8;
            f16x8_t ah = *(const f16x8_t*)(lQh + ao);
            f16x8_t al = *(const f16x8_t*)(lQl + ao);
#pragma unroll
            for (int j = 0; j < 4; j++) {
                int bo = (s * 64 + j * 16 + mrow) * 32 + kg * 8;
                f16x8_t bhv = *(const f16x8_t*)(lBh + bo);
                f16x8_t blv = *(const f16x8_t*)(lBl + bo);
                acc1[j] = __builtin_amdgcn_mfma_f32_16x16x32_f16(ah, bhv, acc1[j], 0, 0, 0);
                acc1[j] = __builtin_amdgcn_mfma_f32_16x16x32_f16(al, bhv, acc1[j], 0, 0, 0);
                acc1[j] = __builtin_amdgcn_mfma_f32_16x16x32_f16(ah, blv, acc1[j], 0, 0, 0);
            }
        }
#pragma unroll
        for (int r = 0; r < 4; r++) {
            float cm = fmaxf(fmaxf(acc1[0][r], acc1[1][r]), fmaxf(acc1[2][r], acc1[3][r]));
            cm = fmaxf(cm, __shfl_xor(cm, 1));
            cm = fmaxf(cm, __shfl_xor(cm, 2));
            cm = fmaxf(cm, __shfl_xor(cm, 4));
            cm = fmaxf(cm, __shfl_xor(cm, 8));
            float mn = fmaxf(m_[r], cm);
            float f = __expf(m_[r] - mn);
            float p0 = __expf(acc1[0][r] - mn);
            float p1 = __expf(acc1[1][r] - mn);
            float p2 = __expf(acc1[2][r] - mn);
            float p3 = __expf(acc1[3][r] - mn);
            float ps = p0 + p1 + p2 + p3;
            ps += __shfl_xor(ps, 1);
            ps += __shfl_xor(ps, 2);
            ps += __shfl_xor(ps, 4);
            ps += __shfl_xor(ps, 8);
            l_[r] = l_[r] * f + ps;
            m_[r] = mn;
#pragma unroll
            for (int j = 0; j < 4; j++) oacc[j][r] *= f;
            int row = w * 16 + kg * 4 + r;
            float pv[4] = {p0, p1, p2, p3};
#pragma unroll
            for (int j = 0; j < 4; j++) {
                unsigned short ph_, pl_;
                split2(pv[j], ph_, pl_);
                int col = j * 16 + mrow;
                int off = ((col >> 5) * 64 + row) * 32 + (col & 31);
                lPh[off] = ph_; lPl[off] = pl_;
            }
        }
        __syncthreads();
#pragma unroll
        for (int s = 0; s < 2; s++) {
            int ao = (s * 64 + w * 16 + mrow) * 32 + kg * 8;
            f16x8_t ph = *(const f16x8_t*)(lPh + ao);
            f16x8_t pl = *(const f16x8_t*)(lPl + ao);
#pragma unroll
            for (int j = 0; j < 4; j++) {
                int bo = (s * 64 + j * 16 + mrow) * 32 + kg * 8;
                f16x8_t vh = *(const f16x8_t*)(lVh + bo);
                f16x8_t vl = *(const f16x8_t*)(lVl + bo);
                oacc[j] = __builtin_amdgcn_mfma_f32_16x16x32_f16(ph, vh, oacc[j], 0, 0, 0);
                oacc[j] = __builtin_amdgcn_mfma_f32_16x16x32_f16(pl, vh, oacc[j], 0, 0, 0);
                oacc[j] = __builtin_amdgcn_mfma_f32_16x16x32_f16(ph, vl, oacc[j], 0, 0, 0);
            }
        }
    }
#pragma unroll
    for (int r = 0; r < 4; r++) {
        int rg = r0 + w * 16 + kg * 4 + r;
        size_t base = (size_t)(bh * KS3 + ks) * LM + rg;
        if (mrow == 0) {
            ml[base * 2 + 0] = m_[r];
            ml[base * 2 + 1] = l_[r];
        }
#pragma unroll
        for (int j = 0; j < 4; j++)
            part[base * DH + j * 16 + mrow] = oacc[j][r];
    }
}

// combine split-K partials with m/l rescale; writes normalized a3v (fp32)
__global__ void k_attn3_reduce(const float* __restrict__ part, const float* __restrict__ ml,
                               float* __restrict__ a3v) {
    int idx = blockIdx.x * 256 + threadIdx.x;
    if (idx >= BH * LM * DH) return;
    int d = idx & 63;
    int r = (idx >> 6) & (LM - 1);
    int bh = idx >> 14;
    float M = -1e30f;
    for (int ks = 0; ks < KS3; ks++)
        M = fmaxf(M, ml[((size_t)(bh * KS3 + ks) * LM + r) * 2]);
    float L = 0.f, s = 0.f;
    for (int ks = 0; ks < KS3; ks++) {
        size_t base = (size_t)(bh * KS3 + ks) * LM + r;
        float f = __expf(ml[base * 2] - M);
        L += ml[base * 2 + 1] * f;
        s += part[base * DH + d] * f;
    }
    a3v[((size_t)bh * LM + r) * DH + d] = s / L;
}

// ---------------- FUSED residual conv + split: actb = split(attn_out + conv33(V)) ----------------
// grid (ceil(NT/64), BH). Stages V[96][64] in LDS once per 64-token tile.
__global__ __launch_bounds__(256) void k_res_split(
        const float* __restrict__ V, const float* __restrict__ rk,
        const float* __restrict__ attn_out,
        unsigned short* __restrict__ yh, unsigned short* __restrict__ yl) {
    int tt = blockIdx.x, bh = blockIdx.y;
    int b = bh / NHEADS, hh = bh % NHEADS;
    int tok0 = tt * 64;
    __shared__ float Vs[96][64];
    __shared__ float k33[33];
    int tid = threadIdx.x;
    if (tid < 33) k33[tid] = rk[hh * 33 + tid];
    // stage V rows [tok0+PADT-16, tok0+PADT+80) — 96 rows x 64 cols
    int g0 = tok0 + PADT - 16;
#pragma unroll
    for (int u = 0; u < 6; u++) {
        int idx = tid + u * 256;           // 0..1535 float4 slots
        int row = idx >> 4, c4 = (idx & 15) * 4;
        int g = g0 + row;
        float4 v = make_float4(0.f, 0.f, 0.f, 0.f);
        if (g < NP) v = *(const float4*)(V + ((size_t)bh * NP + g) * DH + c4);
        *(float4*)&Vs[row][c4] = v;
    }
    __syncthreads();
    int d = tid & 63, wq = tid >> 6;
#pragma unroll
    for (int i = 0; i < 16; i++) {
        int lt = wq + i * 4;               // local token 0..63
        int tok = tok0 + lt;
        if (tok >= NT) continue;
        float s = 0.f;
#pragma unroll
        for (int u = 0; u < 33; u++) s += Vs[lt + u][d] * k33[u];
        size_t row = (size_t)b * NT + tok;
        float v = attn_out[row * DIM + hh * DH + d] + s;
        unsigned short h, l; split2(v, h, l);
        yh[row * DIM + hh * DH + d] = h;
        yl[row * DIM + hh * DH + d] = l;
    }
}

// ---------------- PPEG ----------------
__global__ void k_combine(const float* __restrict__ k7, const float* __restrict__ b7,
                          const float* __restrict__ k5, const float* __restrict__ b5,
                          const float* __restrict__ k3, const float* __restrict__ b3,
                          float* __restrict__ Kc, float* __restrict__ biasC) {
    int tap = blockIdx.y;
    int c = blockIdx.x * 256 + threadIdx.x;
    if (c >= DIM) return;
    int dy = tap / 7 - 3, dx = tap % 7 - 3;
    int ady = dy < 0 ? -dy : dy, adx = dx < 0 ? -dx : dx;
    float w = k7[(size_t)c * 49 + tap];
    if (ady <= 2 && adx <= 2) w += k5[(size_t)c * 25 + (dy + 2) * 5 + (dx + 2)];
    if (ady <= 1 && adx <= 1) w += k3[(size_t)c * 9 + (dy + 1) * 3 + (dx + 1)];
    if (dy == 0 && dx == 0) w += 1.0f;
    Kc[(size_t)tap * DIM + c] = w;
    if (tap == 0) biasC[c] = b7[c] + b5[c] + b3[c];
}

// LDS-tiled PPEG: 32x32 pixel tile, 8-channel group, halo 3
#define PT 32
#define PH 38
__global__ __launch_bounds__(256) void k_ppeg2(
        const float* __restrict__ h1, const float* __restrict__ Kc,
        const float* __restrict__ biasC, float* __restrict__ h2) {
    int xt = blockIdx.x, yt = blockIdx.y;
    int bz = blockIdx.z;
    int b = bz >> 6, cg = bz & 63, c0 = cg * 8;
    __shared__ __align__(16) float sin2[PH * PH * 8];
    __shared__ __align__(16) float wk2[49 * 8];
    __shared__ float sb[8];
    int tid = threadIdx.x;
    for (int i2 = tid; i2 < 392; i2 += 256) {
        int tap = i2 >> 3, ch = i2 & 7;
        wk2[tap * 8 + ch] = Kc[(size_t)tap * DIM + c0 + ch];
    }
    if (tid < 8) sb[tid] = biasC[c0 + tid];
    for (int p = tid; p < PH * PH; p += 256) {
        int ly = p / PH, lx = p % PH;
        int gy = yt * PT + ly - 3, gx = xt * PT + lx - 3;
        float4 v0 = make_float4(0.f, 0.f, 0.f, 0.f), v1 = v0;
        if ((unsigned)gy < 128u && (unsigned)gx < 128u) {
            const float* src = h1 + ((size_t)b * NT + 1 + (size_t)gy * 128 + gx) * DIM + c0;
            v0 = *(const float4*)src;
            v1 = *(const float4*)(src + 4);
        }
        *(float4*)&sin2[p * 8] = v0;
        *(float4*)&sin2[p * 8 + 4] = v1;
    }
    __syncthreads();
    int px = tid & 31, py0 = tid >> 5;
    for (int ry = 0; ry < 4; ry++) {
        int py = py0 + ry * 8;
        float accv[8];
#pragma unroll
        for (int ch = 0; ch < 8; ch++) accv[ch] = sb[ch];
        for (int dy = 0; dy < 7; dy++)
#pragma unroll
            for (int dx = 0; dx < 7; dx++) {
                int pi = (py + dy) * PH + px + dx;
                float4 s0 = *(const float4*)&sin2[pi * 8];
                float4 s1 = *(const float4*)&sin2[pi * 8 + 4];
                int tp = dy * 7 + dx;
                float4 w0 = *(const float4*)&wk2[tp * 8];
                float4 w1 = *(const float4*)&wk2[tp * 8 + 4];
                accv[0] += s0.x * w0.x; accv[1] += s0.y * w0.y;
                accv[2] += s0.z * w0.z; accv[3] += s0.w * w0.w;
                accv[4] += s1.x * w1.x; accv[5] += s1.y * w1.y;
                accv[6] += s1.z * w1.z; accv[7] += s1.w * w1.w;
            }
        float* dst = h2 + ((size_t)b * NT + 1 + (size_t)(yt * PT + py) * 128 + xt * PT + px) * DIM + c0;
        *(float4*)dst = make_float4(accv[0], accv[1], accv[2], accv[3]);
        *(float4*)(dst + 4) = make_float4(accv[4], accv[5], accv[6], accv[7]);
    }
}

// ---------------- cls-only attention tail (attention #2) ----------------
__global__ __launch_bounds__(256) void k_cls_attn(
        const float* __restrict__ q, const float* __restrict__ kl,
        const float* __restrict__ M2, const float* __restrict__ V,
        const float* __restrict__ rk, float* __restrict__ attn_cls) {
    int bh = blockIdx.x;
    int b = bh / NHEADS, hh = bh % NHEADS;
    int tid = threadIdx.x;
    __shared__ float qr[DH];
    __shared__ float sc[LM];
    __shared__ float red[256];
    if (tid < DH) qr[tid] = q[((size_t)bh * NP + PADT) * DH + tid];
    __syncthreads();
    float s = 0.f;
    const float* kp = kl + ((size_t)bh * LM + tid) * DH;
    for (int d2 = 0; d2 < DH; d2++) s += qr[d2] * kp[d2];
    red[tid] = s;
    __syncthreads();
    for (int o = 128; o > 0; o >>= 1) { if (tid < o) red[tid] = fmaxf(red[tid], red[tid + o]); __syncthreads(); }
    float mx = red[0];
    __syncthreads();
    float e = __expf(s - mx);
    red[tid] = e;
    __syncthreads();
    for (int o = 128; o > 0; o >>= 1) { if (tid < o) red[tid] += red[tid + o]; __syncthreads(); }
    float tot = red[0];
    sc[tid] = e / tot;
    __syncthreads();
    if (tid < DH) {
        int d = tid;
        float o1 = 0.f;
        for (int j = 0; j < LM; j++) o1 += sc[j] * M2[((size_t)bh * LM + j) * DH + d];
        float r2 = 0.f;
        for (int u = 0; u < 33; u++) {
            int tp = PADT - 16 + u;
            r2 += V[((size_t)bh * NP + tp) * DH + d] * rk[hh * 33 + u];
        }
        attn_cls[(size_t)b * DIM + hh * DH + d] = o1 + r2;
    }
}

__global__ __launch_bounds__(256) void k_cls_proj(
        const float* __restrict__ attn_cls, const float* __restrict__ Wout,
        const float* __restrict__ bout, const float* __restrict__ h2, float* __restrict__ h_cls) {
    int b = blockIdx.x, tid = threadIdx.x;
    __shared__ float a[DIM];
    a[tid] = attn_cls[(size_t)b * DIM + tid];
    a[tid + 256] = attn_cls[(size_t)b * DIM + tid + 256];
    __syncthreads();
    for (int c = tid; c < DIM; c += 256) {
        float s = bout[c];
        for (int k2 = 0; k2 < DIM; k2++) s += a[k2] * Wout[(size_t)k2 * DIM + c];
        h_cls[(size_t)b * DIM + c] = h2[(size_t)b * NT * DIM + c] + s;
    }
}

__global__ __launch_bounds__(256) void k_final(
        const float* __restrict__ h_cls, const float* __restrict__ g, const float* __restrict__ bb,
        const float* __restrict__ W2, const float* __restrict__ b2, float* __restrict__ out) {
    int b = blockIdx.x, tid = threadIdx.x;
    const float* x = h_cls + (size_t)b * DIM;
    __shared__ float red[256];
    float v0 = x[tid], v1 = x[tid + 256];
    red[tid] = v0 + v1;
    __syncthreads();
    for (int o = 128; o > 0; o >>= 1) { if (tid < o) red[tid] += red[tid + o]; __syncthreads(); }
    float mu = red[0] * (1.0f / DIM);
    __syncthreads();
    float d0 = v0 - mu, d1 = v1 - mu;
    red[tid] = d0 * d0 + d1 * d1;
    __syncthreads();
    for (int o = 128; o > 0; o >>= 1) { if (tid < o) red[tid] += red[tid + o]; __syncthreads(); }
    float rs = rsqrtf(red[0] * (1.0f / DIM) + LNEPS);
    float y0 = d0 * rs * g[tid] + bb[tid];
    float y1 = d1 * rs * g[tid + 256] + bb[tid + 256];
    red[tid] = y0 * W2[tid] + y1 * W2[tid + 256];
    __syncthreads();
    for (int o = 128; o > 0; o >>= 1) { if (tid < o) red[tid] += red[tid + o]; __syncthreads(); }
    if (tid == 0) out[b] = red[0] + b2[0];
}

// ---------------- host orchestration ----------------
struct AttnBufs {
    float *q, *k, *v, *ql, *kl;
    float *a2, *za, *zb, *xz, *ta, *tb;
    float *S, *part, *ml, *a3v, *M2, *scal;
    float *attn_cls, *h_cls;
    unsigned short *actb_h, *actb_l;
};

static void run_attention(hipStream_t stream, const float* hin, float* h_residual,
                          float* attn_out,
                          const float* lng, const float* lnb,
                          const unsigned short* Wqkvt_h, const unsigned short* Wqkvt_l,
                          const unsigned short* Woutt_h, const unsigned short* Woutt_l,
                          const float* Wout_f32, const float* bout,
                          const float* resk, bool full, const AttnBufs& B_) {
    // split-fp16 operand buffers carved from S (dead outside w1 staging; ~208 MB << 272 MB)
    unsigned short* sp = (unsigned short*)B_.S;
    auto su = [&](size_t n) { unsigned short* p = sp; sp += (n + 63) & ~(size_t)63; return p; };
    const size_t NQ = (size_t)BH * NP * DH;
    const size_t NL = (size_t)BH * LM * DH;
    unsigned short *qsh = su(NQ), *qsl = su(NQ);
    unsigned short *ksh = su(NQ), *ksl = su(NQ);
    unsigned short *vth = su(NQ), *vtl = su(NQ);
    unsigned short *qlsh = su(NL), *qlsl = su(NL);
    unsigned short *klsh = su(NL), *klsl = su(NL);
    unsigned short *m2th = su(NL), *m2tl = su(NL);

    k_ln_split<<<dim3(BATCH * NT), 256, 0, stream>>>(hin, lng, lnb, B_.actb_h, B_.actb_l);
    k_zero_pads<<<dim3((BH * PADT * DH + 255) / 256), 256, 0, stream>>>(
        B_.q, B_.k, B_.v, qsh, qsl, ksh, ksl);
    // qkv GEMM with fused q/k split epilogue (m-major grid: A fetched once)
    k_qkv_s<<<dim3(MPAD / 128, 12), 256, 0, stream>>>(B_.actb_h, B_.actb_l, Wqkvt_h, Wqkvt_l,
                                                      B_.q, B_.k, B_.v, qsh, qsl, ksh, ksl);
    k_vt_split<<<dim3(NP / 64, BH), 256, 0, stream>>>(B_.v, vth, vtl);
    k_landmark<<<dim3(1, LM, BH), 64, 0, stream>>>(B_.q, B_.ql, qlsh, qlsl);
    k_landmark<<<dim3(1, LM, BH), 64, 0, stream>>>(B_.k, B_.kl, klsh, klsl);
    k_scores<<<dim3(LM / 64, LM / 64, BH), 256, 0, stream>>>(B_.ql, B_.kl, B_.a2, LM, LM);
    k_softmax<<<dim3(BH * LM), 256, 0, stream>>>(B_.a2, LM);
    hipMemsetAsync(B_.scal, 0, 2 * sizeof(float), stream);
    k_pinv_scal<<<dim3(BH), 256, 0, stream>>>(B_.a2, B_.scal);
    k_z0<<<dim3(1, LM, BH), 256, 0, stream>>>(B_.a2, B_.scal, B_.za);
    float* zc = B_.za; float* zn = B_.zb;
    // Newton-Schulz, diag_sub fused into GEMM epilogue
    for (int it = 0; it < 6; it++) {
        k_gemm_b64<<<dim3(4, 4, BH), 256, 0, stream>>>(B_.a2, zc, B_.xz, nullptr, LM, LM, LM, 1.f, 0.f, 0.f);
        k_gemm_b64<<<dim3(4, 4, BH), 256, 0, stream>>>(B_.xz, B_.xz, B_.tb, B_.xz, LM, LM, LM, 1.f, -7.f, 15.f);
        k_gemm_b64<<<dim3(4, 4, BH), 256, 0, stream>>>(B_.xz, B_.tb, B_.ta, nullptr, LM, LM, LM, -1.f, 0.f, 13.f);
        k_gemm_b64<<<dim3(4, 4, BH), 256, 0, stream>>>(zc, B_.ta, zn, nullptr, LM, LM, LM, 0.25f, 0.f, 0.f);
        std::swap(zc, zn);
    }
    // fused attn3 (MFMA): scores + online softmax + P@V (split-K over NP)
    k_attn3_mfma<<<dim3(KS3, LM / 64, BH), 256, 0, stream>>>(qlsh, qlsl, ksh, ksl, vth, vtl, B_.part, B_.ml);
    k_attn3_reduce<<<dim3(BH * LM * DH / 256), 256, 0, stream>>>(B_.part, B_.ml, B_.a3v);
    k_gemm_b64<<<dim3(1, 4, BH), 256, 0, stream>>>(zc, B_.a3v, B_.M2, nullptr, LM, DH, LM, 1.f, 0.f, 0.f);
    if (full) {
        k_m2t_split<<<dim3(LM / 64, BH), 256, 0, stream>>>(B_.M2, m2th, m2tl);
        k_attn1_mfma<<<dim3((NT + 63) / 64, BH), 256, 0, stream>>>(qsh, qsl, klsh, klsl, m2th, m2tl, attn_out);
        // fused: conv(V) + attn_out -> split fp16 actb
        k_res_split<<<dim3((NT + 63) / 64, BH), 256, 0, stream>>>(B_.v, resk, attn_out, B_.actb_h, B_.actb_l);
        k_outproj_s<<<dim3(MPAD / 128, 4), 256, 0, stream>>>(B_.actb_h, B_.actb_l, Woutt_h, Woutt_l, bout, h_residual);
    } else {
        k_cls_attn<<<dim3(BH), 256, 0, stream>>>(B_.q, B_.kl, B_.M2, B_.v, resk, B_.attn_cls);
        k_cls_proj<<<dim3(BATCH), 256, 0, stream>>>(B_.attn_cls, Wout_f32, bout, hin, B_.h_cls);
    }
}

extern "C" void kernel_launch(void* const* d_in, const int* in_sizes, int n_in,
                              void* d_out, int out_size, void* d_ws, size_t ws_size,
                              hipStream_t stream) {
    const float* features = (const float*)d_in[0];
    const float* W1    = (const float*)d_in[1];
    const float* b1    = (const float*)d_in[2];
    const float* cls   = (const float*)d_in[3];
    const float* ln1_g = (const float*)d_in[4];
    const float* ln1_b = (const float*)d_in[5];
    const float* Wqkv1 = (const float*)d_in[6];
    const float* Wout1 = (const float*)d_in[7];
    const float* bout1 = (const float*)d_in[8];
    const float* resk1 = (const float*)d_in[9];
    const float* ln2_g = (const float*)d_in[10];
    const float* ln2_b = (const float*)d_in[11];
    const float* Wqkv2 = (const float*)d_in[12];
    const float* Wout2 = (const float*)d_in[13];
    const float* bout2 = (const float*)d_in[14];
    const float* resk2 = (const float*)d_in[15];
    const float* k7    = (const float*)d_in[16];
    const float* b7c   = (const float*)d_in[17];
    const float* k5    = (const float*)d_in[18];
    const float* b5c   = (const float*)d_in[19];
    const float* k3    = (const float*)d_in[20];
    const float* b3c   = (const float*)d_in[21];
    const float* lnf_g = (const float*)d_in[22];
    const float* lnf_b = (const float*)d_in[23];
    const float* W2    = (const float*)d_in[24];
    const float* b2    = (const float*)d_in[25];
    float* out = (float*)d_out;

    float* ws = (float*)d_ws;
    size_t off = 0;
    auto alloc = [&](size_t n) { float* p = ws + off; off += (n + 63) & ~(size_t)63; return p; };
    float* h1  = alloc((size_t)BATCH * NT * DIM);
    float* h2  = alloc((size_t)BATCH * NT * DIM);   // also attn_out of layer 1
    AttnBufs Bu;
    Bu.q    = alloc((size_t)BH * NP * DH);
    Bu.k    = alloc((size_t)BH * NP * DH);
    Bu.v    = alloc((size_t)BH * NP * DH);
    Bu.S    = alloc((size_t)BH * NP * LM);          // aliased: feat hi/lo (f16), attn split bufs
    Bu.ql   = alloc((size_t)BH * LM * DH);
    Bu.kl   = alloc((size_t)BH * LM * DH);
    Bu.a2   = alloc((size_t)BH * LM * LM);
    Bu.za   = alloc((size_t)BH * LM * LM);
    Bu.zb   = alloc((size_t)BH * LM * LM);
    Bu.xz   = alloc((size_t)BH * LM * LM);
    Bu.ta   = alloc((size_t)BH * LM * LM);
    Bu.tb   = alloc((size_t)BH * LM * LM);
    Bu.part = alloc((size_t)BH * KS3 * LM * DH);
    Bu.ml   = alloc((size_t)BH * KS3 * LM * 2);
    Bu.a3v  = alloc((size_t)BH * LM * DH);
    Bu.M2   = alloc((size_t)BH * LM * DH);
    Bu.scal = alloc(64);
    Bu.attn_cls = alloc(BATCH * DIM);
    Bu.h_cls    = alloc(BATCH * DIM);
    float* Kc    = alloc(49 * DIM);
    float* biasC = alloc(DIM);
    Bu.actb_h = (unsigned short*)alloc((size_t)MPAD * DIM / 2);
    Bu.actb_l = (unsigned short*)alloc((size_t)MPAD * DIM / 2);
    unsigned short* W1t_h   = (unsigned short*)alloc((size_t)DIM * INDIM / 2);
    unsigned short* W1t_l   = (unsigned short*)alloc((size_t)DIM * INDIM / 2);
    unsigned short* Wqkvt_h = (unsigned short*)alloc((size_t)DIM * 3 * DIM / 2);  // shared by both layers
    unsigned short* Wqkvt_l = (unsigned short*)alloc((size_t)DIM * 3 * DIM / 2);
    unsigned short* Wo1t_h  = (unsigned short*)alloc((size_t)DIM * DIM / 2);
    unsigned short* Wo1t_l  = (unsigned short*)alloc((size_t)DIM * DIM / 2);
    // feat hi/lo alias into S (S unused until after w1 GEMM)
    unsigned short* featb_h = (unsigned short*)Bu.S;
    unsigned short* featb_l = featb_h + (size_t)BATCH * 16384 * INDIM;

    // zero pad rows of activation buffers (rows MROWS..MPAD), once per launch
    hipMemsetAsync(Bu.actb_h + (size_t)MROWS * DIM, 0, (size_t)(MPAD - MROWS) * DIM * 2, stream);
    hipMemsetAsync(Bu.actb_l + (size_t)MROWS * DIM, 0, (size_t)(MPAD - MROWS) * DIM * 2, stream);

    // weight prep (split f16, transposed to [N][K])
    k_wt_split<<<dim3((INDIM * DIM + 255) / 256), 256, 0, stream>>>(W1, W1t_h, W1t_l, INDIM, DIM);
    k_wt_split<<<dim3((DIM * 3 * DIM + 255) / 256), 256, 0, stream>>>(Wqkv1, Wqkvt_h, Wqkvt_l, DIM, 3 * DIM);
    k_wt_split<<<dim3((DIM * DIM + 255) / 256), 256, 0, stream>>>(Wout1, Wo1t_h, Wo1t_l, DIM, DIM);
    // features -> split f16
    k_cvt_split<<<dim3((BATCH * 16384 * INDIM / 4 + 255) / 256), 256, 0, stream>>>(
        features, featb_h, featb_l, BATCH * 16384 * INDIM / 4);

    // 1) h = relu(features @ W1 + b1), prepend cls   (m-major grid)
    k_set_cls<<<dim3(4), 256, 0, stream>>>(cls, h1);
    k_w1_s<<<dim3(256, 4), 256, 0, stream>>>(featb_h, featb_l, W1t_h, W1t_l, b1, h1);
    // 2) h += nystrom_attention(LN(h))  (full)
    run_attention(stream, h1, h1, h2, ln1_g, ln1_b, Wqkvt_h, Wqkvt_l, Wo1t_h, Wo1t_l,
                  nullptr, bout1, resk1, true, Bu);
    // 3) PPEG
    k_combine<<<dim3(2, 49), 256, 0, stream>>>(k7, b7c, k5, b5c, k3, b3c, Kc, biasC);
    k_ppeg2<<<dim3(4, 4, BATCH * 64), 256, 0, stream>>>(h1, Kc, biasC, h2);
    k_copy_cls<<<dim3(4), 256, 0, stream>>>(h1, h2);
    // 4) second attention — only cls token needed downstream; reuse Wqkv staging buffer
    k_wt_split<<<dim3((DIM * 3 * DIM + 255) / 256), 256, 0, stream>>>(Wqkv2, Wqkvt_h, Wqkvt_l, DIM, 3 * DIM);
    run_attention(stream, h2, nullptr, nullptr, ln2_g, ln2_b, Wqkvt_h, Wqkvt_l, nullptr, nullptr,
                  Wout2, bout2, resk2, false, Bu);
    // 5) final LN on cls + linear head
    k_final<<<dim3(BATCH), 256, 0, stream>>>(Bu.h_cls, lnf_g, lnf_b, W2, b2, out);
}

// Round 10
// 2801.410 us; speedup vs baseline: 1.0317x; 1.0317x over previous
//
#include <hip/hip_runtime.h>
#include <utility>

// ---------------- constants ----------------
#define BATCH   2
#define NT      16385          // tokens incl cls
#define NP      16640          // nystrom-padded length (65*256)
#define PADT    255            // front padding
#define LM      256            // landmarks
#define LAVG    65             // tokens averaged per landmark
#define NHEADS  8
#define DH      64
#define DIM     512
#define INDIM   1536
#define BH      (BATCH*NHEADS)
#define LNEPS   1e-5f
#define QSCALE  0.125f
#define MROWS   (BATCH*NT)     // 32770
#define MPAD    32896          // 257*128, padded rows for MFMA GEMMs
// flash split for attn3: NP = KS3 * KC3, KC3 multiple of 64
#define KS3     52
#define KC3     320            // 5 chunks of 64

typedef _Float16 f16x8_t __attribute__((ext_vector_type(8)));
typedef float    f32x4_t __attribute__((ext_vector_type(4)));

// split fp32 -> fp16 hi + fp16 lo (hi+lo carries ~22 mantissa bits)
__device__ __forceinline__ void split2(float f, unsigned short& hi, unsigned short& lo) {
    _Float16 h = (_Float16)f;
    float r = f - (float)h;
    _Float16 l = (_Float16)r;
    hi = __builtin_bit_cast(unsigned short, h);
    lo = __builtin_bit_cast(unsigned short, l);
}

__device__ __forceinline__ void async16(const unsigned short* g, unsigned short* l) {
    __builtin_amdgcn_global_load_lds((const __attribute__((address_space(1))) void*)g,
                                     (__attribute__((address_space(3))) void*)l, 16, 0, 0);
}

// XCD-chunked bijective block swizzle (T1, m204 formula): dispatch id -> work id
// such that XCD (id%8) owns a contiguous m-major work range. Returns (m0, n0).
__device__ __forceinline__ int2 xcd_map(int nwg, int ntn) {
    int id = blockIdx.x;
    int c = id & 7, j = id >> 3;
    int q = nwg >> 3, r = nwg & 7;
    int w = (c < r) ? c * (q + 1) + j : r * (q + 1) + (c - r) * q + j;
    return make_int2((w / ntn) * 128, (w % ntn) * 128);
}

// ---------------- tiny kernels ----------------
__global__ void k_set_cls(const float* __restrict__ cls, float* __restrict__ h) {
    int i = blockIdx.x * 256 + threadIdx.x;
    if (i < BATCH * DIM) {
        int b = i / DIM, c = i % DIM;
        h[(size_t)b * NT * DIM + c] = cls[c];
    }
}

__global__ void k_copy_cls(const float* __restrict__ src, float* __restrict__ dst) {
    int i = blockIdx.x * 256 + threadIdx.x;
    if (i < BATCH * DIM) {
        int b = i / DIM, c = i % DIM;
        dst[(size_t)b * NT * DIM + c] = src[(size_t)b * NT * DIM + c];
    }
}

__global__ void k_zero_pads(float* __restrict__ q, float* __restrict__ k, float* __restrict__ v) {
    int idx = blockIdx.x * 256 + threadIdx.x;
    const int per = PADT * DH;
    if (idx < BH * per) {
        int bh = idx / per, rest = idx % per;
        size_t off = (size_t)bh * NP * DH + rest;
        q[off] = 0.f; k[off] = 0.f; v[off] = 0.f;
    }
}

// fp32 -> (hi,lo) fp16 pair, vectorized by 4
__global__ void k_cvt_split(const float* __restrict__ x, unsigned short* __restrict__ yh,
                            unsigned short* __restrict__ yl, int n4) {
    int i = blockIdx.x * 256 + threadIdx.x;
    if (i < n4) {
        float4 v = ((const float4*)x)[i];
        ushort4 oh, ol;
        split2(v.x, oh.x, ol.x); split2(v.y, oh.y, ol.y);
        split2(v.z, oh.z, ol.z); split2(v.w, oh.w, ol.w);
        ((ushort4*)yh)[i] = oh;
        ((ushort4*)yl)[i] = ol;
    }
}

// W [K][N] fp32 -> Wt [N][K] fp16 hi/lo
__global__ void k_wt_split(const float* __restrict__ W, unsigned short* __restrict__ Wth,
                           unsigned short* __restrict__ Wtl, int K, int N) {
    int idx = blockIdx.x * 256 + threadIdx.x;
    if (idx < K * N) {
        int k = idx / N, n = idx % N;
        unsigned short h, l;
        split2(W[idx], h, l);
        Wth[(size_t)n * K + k] = h;
        Wtl[(size_t)n * K + k] = l;
    }
}

// ---------------- split-fp16 MFMA GEMM core: 128x128 tile, BK=32 ----------------
__device__ __forceinline__ void mfma_core_s(
        const unsigned short* __restrict__ Ah, const unsigned short* __restrict__ Al,
        const unsigned short* __restrict__ Bh, const unsigned short* __restrict__ Bl,
        int K, int m0, int n0,
        unsigned short* lAh, unsigned short* lAl,
        unsigned short* lBh, unsigned short* lBl, f32x4_t acc[4][4]) {
    const int tid = threadIdx.x;
    const int lane = tid & 63, wave = tid >> 6;
    const int wm = (wave >> 1) * 64, wn = (wave & 1) * 64;
    const int mrow = lane & 15, kg = lane >> 4;
    const int arow = tid >> 2, acol = (tid & 3) * 8;
    for (int k0 = 0; k0 < K; k0 += 32) {
        size_t aoff  = (size_t)(m0 + arow) * K + k0 + acol;
        size_t aoff2 = aoff + (size_t)64 * K;
        size_t boff  = (size_t)(n0 + arow) * K + k0 + acol;
        size_t boff2 = boff + (size_t)64 * K;
        async16(Ah + aoff,  lAh + tid * 8);
        async16(Ah + aoff2, lAh + 2048 + tid * 8);
        async16(Al + aoff,  lAl + tid * 8);
        async16(Al + aoff2, lAl + 2048 + tid * 8);
        async16(Bh + boff,  lBh + tid * 8);
        async16(Bh + boff2, lBh + 2048 + tid * 8);
        async16(Bl + boff,  lBl + tid * 8);
        async16(Bl + boff2, lBl + 2048 + tid * 8);
        __syncthreads();
        f16x8_t ah[4], al[4], bh[4], bl[4];
#pragma unroll
        for (int i = 0; i < 4; i++) {
            int ro = (wm + i * 16 + mrow) * 32 + kg * 8;
            ah[i] = *(const f16x8_t*)(lAh + ro);
            al[i] = *(const f16x8_t*)(lAl + ro);
        }
#pragma unroll
        for (int j = 0; j < 4; j++) {
            int ro = (wn + j * 16 + mrow) * 32 + kg * 8;
            bh[j] = *(const f16x8_t*)(lBh + ro);
            bl[j] = *(const f16x8_t*)(lBl + ro);
        }
#pragma unroll
        for (int i = 0; i < 4; i++)
#pragma unroll
            for (int j = 0; j < 4; j++) {
                acc[i][j] = __builtin_amdgcn_mfma_f32_16x16x32_f16(ah[i], bh[j], acc[i][j], 0, 0, 0);
                acc[i][j] = __builtin_amdgcn_mfma_f32_16x16x32_f16(al[i], bh[j], acc[i][j], 0, 0, 0);
                acc[i][j] = __builtin_amdgcn_mfma_f32_16x16x32_f16(ah[i], bl[j], acc[i][j], 0, 0, 0);
            }
        __syncthreads();
    }
}

#define MFMA_LDS \
    __shared__ __align__(16) unsigned short lAh[4096]; \
    __shared__ __align__(16) unsigned short lAl[4096]; \
    __shared__ __align__(16) unsigned short lBh[4096]; \
    __shared__ __align__(16) unsigned short lBl[4096];

// w1: relu(feat @ W1t + b1) -> h1 (with cls row offset). M=32768, K=1536, N=512
// 1-D grid 1024 blocks, XCD-chunked swizzle (4 n-tiles)
__global__ __launch_bounds__(256) void k_w1_s(
        const unsigned short* __restrict__ Ah, const unsigned short* __restrict__ Al,
        const unsigned short* __restrict__ Bh, const unsigned short* __restrict__ Bl,
        const float* __restrict__ bias, float* __restrict__ hout) {
    MFMA_LDS
    f32x4_t acc[4][4] = {};
    int2 mn = xcd_map(1024, 4);
    int m0 = mn.x, n0 = mn.y;
    mfma_core_s(Ah, Al, Bh, Bl, INDIM, m0, n0, lAh, lAl, lBh, lBl, acc);
    int lane = threadIdx.x & 63, wave = threadIdx.x >> 6;
    int wm = (wave >> 1) * 64, wn = (wave & 1) * 64;
    int c16 = lane & 15, kg = lane >> 4;
#pragma unroll
    for (int i = 0; i < 4; i++)
#pragma unroll
        for (int r = 0; r < 4; r++) {
            int row = m0 + wm + i * 16 + kg * 4 + r;
            int b = row >> 14;
            size_t orow = (size_t)row + b + 1;
#pragma unroll
            for (int j = 0; j < 4; j++) {
                int col = n0 + wn + j * 16 + c16;
                float v = acc[i][j][r] + bias[col];
                hout[orow * DIM + col] = fmaxf(v, 0.f);
            }
        }
}

// qkv: act @ Wqkvt -> scatter q,k,v. M=32770(pad 32896), K=512, N=1536
// 1-D grid 3084 blocks, XCD-chunked swizzle (12 n-tiles)
__global__ __launch_bounds__(256) void k_qkv_s(
        const unsigned short* __restrict__ Ah, const unsigned short* __restrict__ Al,
        const unsigned short* __restrict__ Bh, const unsigned short* __restrict__ Bl,
        float* __restrict__ q, float* __restrict__ k, float* __restrict__ v) {
    MFMA_LDS
    f32x4_t acc[4][4] = {};
    int2 mn = xcd_map(3084, 12);
    int m0 = mn.x, n0 = mn.y;
    mfma_core_s(Ah, Al, Bh, Bl, DIM, m0, n0, lAh, lAl, lBh, lBl, acc);
    int lane = threadIdx.x & 63, wave = threadIdx.x >> 6;
    int wm = (wave >> 1) * 64, wn = (wave & 1) * 64;
    int c16 = lane & 15, kg = lane >> 4;
#pragma unroll
    for (int i = 0; i < 4; i++)
#pragma unroll
        for (int r = 0; r < 4; r++) {
            int row = m0 + wm + i * 16 + kg * 4 + r;
            if (row >= MROWS) continue;
            int b = row / NT, tok = row % NT;
            size_t t = (size_t)tok + PADT;
#pragma unroll
            for (int j = 0; j < 4; j++) {
                int col = n0 + wn + j * 16 + c16;
                int sel = col >> 9, hh = (col >> 6) & 7, d = col & 63;
                float vv = acc[i][j][r];
                float* dst = (sel == 0) ? q : (sel == 1) ? k : v;
                if (sel == 0) vv *= QSCALE;
                dst[((size_t)(b * NHEADS + hh) * NP + t) * DH + d] = vv;
            }
        }
}

// outproj: hio += act @ Woutt + bias. M=32770(pad), K=512, N=512
// 1-D grid 1028 blocks, XCD-chunked swizzle (4 n-tiles)
__global__ __launch_bounds__(256) void k_outproj_s(
        const unsigned short* __restrict__ Ah, const unsigned short* __restrict__ Al,
        const unsigned short* __restrict__ Bh, const unsigned short* __restrict__ Bl,
        const float* __restrict__ bias, float* __restrict__ hio) {
    MFMA_LDS
    f32x4_t acc[4][4] = {};
    int2 mn = xcd_map(1028, 4);
    int m0 = mn.x, n0 = mn.y;
    mfma_core_s(Ah, Al, Bh, Bl, DIM, m0, n0, lAh, lAl, lBh, lBl, acc);
    int lane = threadIdx.x & 63, wave = threadIdx.x >> 6;
    int wm = (wave >> 1) * 64, wn = (wave & 1) * 64;
    int c16 = lane & 15, kg = lane >> 4;
#pragma unroll
    for (int i = 0; i < 4; i++)
#pragma unroll
        for (int r = 0; r < 4; r++) {
            int row = m0 + wm + i * 16 + kg * 4 + r;
            if (row >= MROWS) continue;
#pragma unroll
            for (int j = 0; j < 4; j++) {
                int col = n0 + wn + j * 16 + c16;
                hio[(size_t)row * DIM + col] += acc[i][j][r] + bias[col];
            }
        }
}

// ---------------- layernorm -> split fp16 ----------------
__global__ __launch_bounds__(256) void k_ln_split(
        const float* __restrict__ x, const float* __restrict__ g,
        const float* __restrict__ bb, unsigned short* __restrict__ yh,
        unsigned short* __restrict__ yl) {
    size_t row = blockIdx.x;
    const float* xr = x + row * DIM;
    int tid = threadIdx.x;
    __shared__ float red[256];
    float v0 = xr[tid], v1 = xr[tid + 256];
    red[tid] = v0 + v1;
    __syncthreads();
    for (int o = 128; o > 0; o >>= 1) { if (tid < o) red[tid] += red[tid + o]; __syncthreads(); }
    float mu = red[0] * (1.0f / DIM);
    __syncthreads();
    float d0 = v0 - mu, d1 = v1 - mu;
    red[tid] = d0 * d0 + d1 * d1;
    __syncthreads();
    for (int o = 128; o > 0; o >>= 1) { if (tid < o) red[tid] += red[tid + o]; __syncthreads(); }
    float rs = rsqrtf(red[0] * (1.0f / DIM) + LNEPS);
    float y0 = d0 * rs * g[tid] + bb[tid];
    float y1 = d1 * rs * g[tid + 256] + bb[tid + 256];
    unsigned short h, l;
    split2(y0, h, l);
    yh[row * DIM + tid] = h; yl[row * DIM + tid] = l;
    split2(y1, h, l);
    yh[row * DIM + tid + 256] = h; yl[row * DIM + tid + 256] = l;
}

// ---------------- landmarks (fp32 + split fp16 outputs) ----------------
__global__ void k_landmark(const float* __restrict__ x, float* __restrict__ xl,
                           unsigned short* __restrict__ xsh, unsigned short* __restrict__ xsl) {
    int bh = blockIdx.z, i = blockIdx.y, d = threadIdx.x;
    const float* p = x + ((size_t)bh * NP + (size_t)i * LAVG) * DH + d;
    float s = 0.f;
    for (int j = 0; j < LAVG; j++) s += p[(size_t)j * DH];
    float v = s * (1.0f / LAVG);
    size_t o = ((size_t)bh * LM + i) * DH + d;
    xl[o] = v;
    unsigned short h, l; split2(v, h, l);
    xsh[o] = h; xsl[o] = l;
}

// ---------------- V [bh][NP][64] fp32 -> Vt split [bh][64][NP] ----------------
__global__ __launch_bounds__(256) void k_vt_split(
        const float* __restrict__ V, unsigned short* __restrict__ Yh,
        unsigned short* __restrict__ Yl) {
    int t0 = blockIdx.x * 64, bh = blockIdx.y;
    __shared__ float tile[64][65];
    int tid = threadIdx.x;
#pragma unroll
    for (int u = 0; u < 4; u++) {
        int idx = tid + u * 256;
        int row = idx >> 4, c4 = (idx & 15) * 4;
        *(float4*)&tile[row][c4] = *(const float4*)(V + ((size_t)bh * NP + t0 + row) * DH + c4);
    }
    __syncthreads();
    int d = tid >> 2, g16 = (tid & 3) * 16;
    __attribute__((aligned(16))) unsigned short oh[16], ol[16];
#pragma unroll
    for (int u = 0; u < 16; u++) split2(tile[g16 + u][d], oh[u], ol[u]);
    size_t o = ((size_t)bh * DH + d) * NP + t0 + g16;
#pragma unroll
    for (int u = 0; u < 4; u++) {
        *(ushort4*)(Yh + o + u * 4) = *(const ushort4*)&oh[u * 4];
        *(ushort4*)(Yl + o + u * 4) = *(const ushort4*)&ol[u * 4];
    }
}

// ---------------- M2 [bh][256][64] fp32 -> M2t split [bh][64][256] ----------------
__global__ __launch_bounds__(256) void k_m2t_split(
        const float* __restrict__ M2, unsigned short* __restrict__ Yh,
        unsigned short* __restrict__ Yl) {
    int l0 = blockIdx.x * 64, bh = blockIdx.y;
    __shared__ float tile[64][65];
    int tid = threadIdx.x;
#pragma unroll
    for (int u = 0; u < 4; u++) {
        int idx = tid + u * 256;
        int row = idx >> 4, c4 = (idx & 15) * 4;
        *(float4*)&tile[row][c4] = *(const float4*)(M2 + ((size_t)bh * LM + l0 + row) * DH + c4);
    }
    __syncthreads();
    int d = tid >> 2, g16 = (tid & 3) * 16;
    __attribute__((aligned(16))) unsigned short oh[16], ol[16];
#pragma unroll
    for (int u = 0; u < 16; u++) split2(tile[g16 + u][d], oh[u], ol[u]);
    size_t o = ((size_t)bh * DH + d) * LM + l0 + g16;
#pragma unroll
    for (int u = 0; u < 4; u++) {
        *(ushort4*)(Yh + o + u * 4) = *(const ushort4*)&oh[u * 4];
        *(ushort4*)(Yl + o + u * 4) = *(const ushort4*)&ol[u * 4];
    }
}

// ---------------- scores (small, a2 only): C[bh,r,c] = A[bh,r,:]·B[bh,c,:] ----------------
__global__ __launch_bounds__(256) void k_scores(
        const float* __restrict__ A, const float* __restrict__ Bm,
        float* __restrict__ C, int Mrows, int Ncols) {
    int bh = blockIdx.z;
    int c0 = blockIdx.x * 64, r0 = blockIdx.y * 64;
    __shared__ float As[64][DH + 1];
    __shared__ float Bs[64][DH + 1];
    int tid = threadIdx.x;
    int tc = tid & 15, tr = tid >> 4;
#pragma unroll
    for (int rep = 0; rep < 4; rep++) {
        int row = rep * 16 + (tid >> 4);
        int c4 = (tid & 15) * 4;
        float4 va = *(const float4*)(A + ((size_t)bh * Mrows + r0 + row) * DH + c4);
        As[row][c4 + 0] = va.x; As[row][c4 + 1] = va.y; As[row][c4 + 2] = va.z; As[row][c4 + 3] = va.w;
        float4 vb = *(const float4*)(Bm + ((size_t)bh * Ncols + c0 + row) * DH + c4);
        Bs[row][c4 + 0] = vb.x; Bs[row][c4 + 1] = vb.y; Bs[row][c4 + 2] = vb.z; Bs[row][c4 + 3] = vb.w;
    }
    __syncthreads();
    float acc[4][4] = {};
#pragma unroll 8
    for (int kk = 0; kk < DH; kk++) {
        float a_[4], b_[4];
#pragma unroll
        for (int i = 0; i < 4; i++) a_[i] = As[tr * 4 + i][kk];
#pragma unroll
        for (int j = 0; j < 4; j++) b_[j] = Bs[tc * 4 + j][kk];
#pragma unroll
        for (int i = 0; i < 4; i++)
#pragma unroll
            for (int j = 0; j < 4; j++) acc[i][j] += a_[i] * b_[j];
    }
#pragma unroll
    for (int i = 0; i < 4; i++)
#pragma unroll
        for (int j = 0; j < 4; j++)
            C[((size_t)bh * Mrows + r0 + tr * 4 + i) * Ncols + c0 + tc * 4 + j] = acc[i][j];
}

// ---------------- row softmax, in place (small, a2 only) ----------------
__global__ __launch_bounds__(256) void k_softmax(float* __restrict__ S, int len) {
    size_t row = blockIdx.x;
    float* p = S + row * (size_t)len;
    int tid = threadIdx.x;
    __shared__ float red[256];
    float m = -1e30f;
    for (int i = tid; i < len; i += 256) m = fmaxf(m, p[i]);
    red[tid] = m;
    __syncthreads();
    for (int o = 128; o > 0; o >>= 1) { if (tid < o) red[tid] = fmaxf(red[tid], red[tid + o]); __syncthreads(); }
    m = red[0];
    __syncthreads();
    float s = 0.f;
    for (int i = tid; i < len; i += 256) s += __expf(p[i] - m);
    red[tid] = s;
    __syncthreads();
    for (int o = 128; o > 0; o >>= 1) { if (tid < o) red[tid] += red[tid + o]; __syncthreads(); }
    float inv = 1.0f / red[0];
    for (int i = tid; i < len; i += 256) p[i] = __expf(p[i] - m) * inv;
}

// ---------------- pinv scalars ----------------
__global__ __launch_bounds__(256) void k_pinv_scal(const float* __restrict__ a2, float* __restrict__ scal) {
    int bh = blockIdx.x, tid = threadIdx.x;
    const float* p = a2 + (size_t)bh * LM * LM;
    float cs = 0.f, rs = 0.f;
    for (int i = 0; i < LM; i++) cs += fabsf(p[(size_t)i * LM + tid]);
    for (int j = 0; j < LM; j++) rs += fabsf(p[(size_t)tid * LM + j]);
    __shared__ float red[256];
    red[tid] = rs;
    __syncthreads();
    for (int o = 128; o > 0; o >>= 1) { if (tid < o) red[tid] = fmaxf(red[tid], red[tid + o]); __syncthreads(); }
    if (tid == 0) atomicMax((int*)&scal[0], __float_as_int(red[0]));
    __syncthreads();
    red[tid] = cs;
    __syncthreads();
    for (int o = 128; o > 0; o >>= 1) { if (tid < o) red[tid] = fmaxf(red[tid], red[tid + o]); __syncthreads(); }
    if (tid == 0) atomicMax((int*)&scal[1], __float_as_int(red[0]));
}

__global__ void k_z0(const float* __restrict__ a2, const float* __restrict__ scal, float* __restrict__ z) {
    int bh = blockIdx.z, i = blockIdx.y, j = threadIdx.x;
    float inv = 1.0f / (scal[0] * scal[1]);
    z[((size_t)bh * LM + i) * LM + j] = a2[((size_t)bh * LM + j) * LM + i] * inv;
}

// ---------------- batched fp32 GEMM, 64x64 tile, BK=32, 4x4/thread ----------------
// C = alpha*(A@B) + beta*E + dval*I   (E optional, fp32 row-major same shape as C)
__global__ __launch_bounds__(256) void k_gemm_b64(
        const float* __restrict__ A, const float* __restrict__ Bm, float* __restrict__ C,
        const float* __restrict__ E, int Mr, int Nc, int Kd,
        float alpha, float beta, float dval) {
    int bh = blockIdx.z;
    int r0 = blockIdx.y * 64, c0 = blockIdx.x * 64;
    const float* Ab = A + (size_t)bh * Mr * Kd;
    const float* Bb = Bm + (size_t)bh * Kd * Nc;
    __shared__ float As[64][36];
    __shared__ float Bs[32][68];
    int tid = threadIdx.x;
    int tr = tid >> 4, tc = tid & 15;
    int arw = tid >> 2, ac8 = (tid & 3) * 8;
    int brw = tid >> 3, bc8 = (tid & 7) * 8;
    float acc[4][4] = {};
    for (int k0 = 0; k0 < Kd; k0 += 32) {
        float4 a0 = *(const float4*)(Ab + (size_t)(r0 + arw) * Kd + k0 + ac8);
        float4 a1 = *(const float4*)(Ab + (size_t)(r0 + arw) * Kd + k0 + ac8 + 4);
        *(float4*)&As[arw][ac8] = a0;
        *(float4*)&As[arw][ac8 + 4] = a1;
        float4 b0 = *(const float4*)(Bb + (size_t)(k0 + brw) * Nc + c0 + bc8);
        float4 b1 = *(const float4*)(Bb + (size_t)(k0 + brw) * Nc + c0 + bc8 + 4);
        *(float4*)&Bs[brw][bc8] = b0;
        *(float4*)&Bs[brw][bc8 + 4] = b1;
        __syncthreads();
#pragma unroll
        for (int kk = 0; kk < 32; kk++) {
            float a_[4], b_[4];
#pragma unroll
            for (int i = 0; i < 4; i++) a_[i] = As[tr * 4 + i][kk];
#pragma unroll
            for (int j = 0; j < 4; j++) b_[j] = Bs[kk][tc * 4 + j];
#pragma unroll
            for (int i = 0; i < 4; i++)
#pragma unroll
                for (int j = 0; j < 4; j++) acc[i][j] += a_[i] * b_[j];
        }
        __syncthreads();
    }
#pragma unroll
    for (int i = 0; i < 4; i++)
#pragma unroll
        for (int j = 0; j < 4; j++) {
            int r = r0 + tr * 4 + i, c = c0 + tc * 4 + j;
            float vv = alpha * acc[i][j] + ((r == c) ? dval : 0.f);
            if (E) vv += beta * E[(size_t)bh * Mr * Nc + (size_t)r * Nc + c];
            C[(size_t)bh * Mr * Nc + (size_t)r * Nc + c] = vv;
        }
}

// ================ MFMA fused attention ================
// Tile layout in LDS (split-fp16): [kstep s][row][32] ushort, off = (s*64+row)*32+kk.
// A/B fragment conventions identical to mfma_core_s (verified):
//   A frag: row = lane&15 (+ row-block), k-octet = (lane>>4)*8;  B same on Bt rows.
//   C/D: col = lane&15, row = (lane>>4)*4 + reg.
// Each wave owns output rows w*16..w*16+15 and iterates 4 col-fragments j.

// attn1: softmax(q @ kl^T) @ M2 -> attn_out.  grid (ceil(NT/64), BH)
__global__ __launch_bounds__(256, 2) void k_attn1_mfma(
        const unsigned short* __restrict__ qsh, const unsigned short* __restrict__ qsl,
        const unsigned short* __restrict__ klsh, const unsigned short* __restrict__ klsl,
        const unsigned short* __restrict__ m2h, const unsigned short* __restrict__ m2l,
        float* __restrict__ attn_out) {
    int tt = blockIdx.x, bh = blockIdx.y;
    int b = bh / NHEADS, hh = bh % NHEADS;
    int tok0 = tt * 64;
    __shared__ __align__(16) unsigned short lQh[4096], lQl[4096];
    __shared__ __align__(16) unsigned short lBh[4096], lBl[4096];
    __shared__ __align__(16) unsigned short lPh[4096], lPl[4096];
    __shared__ __align__(16) unsigned short lVh[4096], lVl[4096];
    int tid = threadIdx.x;
    int lane = tid & 63, w = tid >> 6;
    int mrow = lane & 15, kg = lane >> 4;
    int arow = tid >> 2, acol = (tid & 3) * 8;
    {   // stage q tile once (row-clamped per thread; clamped rows are dead)
        int tok = tok0 + arow; if (tok >= NT) tok = NT - 1;
        size_t src = ((size_t)bh * NP + tok + PADT) * DH + acol;
        async16(qsh + src,      lQh + tid * 8);
        async16(qsh + src + 32, lQh + 2048 + tid * 8);
        async16(qsl + src,      lQl + tid * 8);
        async16(qsl + src + 32, lQl + 2048 + tid * 8);
    }
    float m_[4], l_[4];
    f32x4_t oacc[4];
#pragma unroll
    for (int r = 0; r < 4; r++) { m_[r] = -1e30f; l_[r] = 0.f; }
#pragma unroll
    for (int j = 0; j < 4; j++) oacc[j] = (f32x4_t){0.f, 0.f, 0.f, 0.f};
    for (int ck = 0; ck < 4; ck++) {
        if (ck) __syncthreads();   // prev PV done with lP/lV; prev scores done with lB
        {
            size_t sb = ((size_t)bh * LM + ck * 64 + arow) * DH + acol;
            async16(klsh + sb,      lBh + tid * 8);
            async16(klsh + sb + 32, lBh + 2048 + tid * 8);
            async16(klsl + sb,      lBl + tid * 8);
            async16(klsl + sb + 32, lBl + 2048 + tid * 8);
            size_t sv = ((size_t)bh * DH + arow) * LM + ck * 64 + acol;
            async16(m2h + sv,      lVh + tid * 8);
            async16(m2h + sv + 32, lVh + 2048 + tid * 8);
            async16(m2l + sv,      lVl + tid * 8);
            async16(m2l + sv + 32, lVl + 2048 + tid * 8);
        }
        __syncthreads();   // stages visible (covers lQ on ck==0)
        f32x4_t acc1[4];
#pragma unroll
        for (int j = 0; j < 4; j++) acc1[j] = (f32x4_t){0.f, 0.f, 0.f, 0.f};
#pragma unroll
        for (int s = 0; s < 2; s++) {
            int ao = (s * 64 + w * 16 + mrow) * 32 + kg * 8;
            f16x8_t ah = *(const f16x8_t*)(lQh + ao);
            f16x8_t al = *(const f16x8_t*)(lQl + ao);
#pragma unroll
            for (int j = 0; j < 4; j++) {
                int bo = (s * 64 + j * 16 + mrow) * 32 + kg * 8;
                f16x8_t bhv = *(const f16x8_t*)(lBh + bo);
                f16x8_t blv = *(const f16x8_t*)(lBl + bo);
                acc1[j] = __builtin_amdgcn_mfma_f32_16x16x32_f16(ah, bhv, acc1[j], 0, 0, 0);
                acc1[j] = __builtin_amdgcn_mfma_f32_16x16x32_f16(al, bhv, acc1[j], 0, 0, 0);
                acc1[j] = __builtin_amdgcn_mfma_f32_16x16x32_f16(ah, blv, acc1[j], 0, 0, 0);
            }
        }
        // online softmax; each lane owns rows w*16+kg*4+r, cols j*16+mrow
#pragma unroll
        for (int r = 0; r < 4; r++) {
            float cm = fmaxf(fmaxf(acc1[0][r], acc1[1][r]), fmaxf(acc1[2][r], acc1[3][r]));
            cm = fmaxf(cm, __shfl_xor(cm, 1));
            cm = fmaxf(cm, __shfl_xor(cm, 2));
            cm = fmaxf(cm, __shfl_xor(cm, 4));
            cm = fmaxf(cm, __shfl_xor(cm, 8));
            float mn = fmaxf(m_[r], cm);
            float f = __expf(m_[r] - mn);
            float p0 = __expf(acc1[0][r] - mn);
            float p1 = __expf(acc1[1][r] - mn);
            float p2 = __expf(acc1[2][r] - mn);
            float p3 = __expf(acc1[3][r] - mn);
            float ps = p0 + p1 + p2 + p3;
            ps += __shfl_xor(ps, 1);
            ps += __shfl_xor(ps, 2);
            ps += __shfl_xor(ps, 4);
            ps += __shfl_xor(ps, 8);
            l_[r] = l_[r] * f + ps;
            m_[r] = mn;
#pragma unroll
            for (int j = 0; j < 4; j++) oacc[j][r] *= f;
            int row = w * 16 + kg * 4 + r;
            float pv[4] = {p0, p1, p2, p3};
#pragma unroll
            for (int j = 0; j < 4; j++) {
                unsigned short ph_, pl_;
                split2(pv[j], ph_, pl_);
                int col = j * 16 + mrow;
                int off = ((col >> 5) * 64 + row) * 32 + (col & 31);
                lPh[off] = ph_; lPl[off] = pl_;
            }
        }
        __syncthreads();   // P visible
#pragma unroll
        for (int s = 0; s < 2; s++) {
            int ao = (s * 64 + w * 16 + mrow) * 32 + kg * 8;
            f16x8_t ph = *(const f16x8_t*)(lPh + ao);
            f16x8_t pl = *(const f16x8_t*)(lPl + ao);
#pragma unroll
            for (int j = 0; j < 4; j++) {
                int bo = (s * 64 + j * 16 + mrow) * 32 + kg * 8;
                f16x8_t vh = *(const f16x8_t*)(lVh + bo);
                f16x8_t vl = *(const f16x8_t*)(lVl + bo);
                oacc[j] = __builtin_amdgcn_mfma_f32_16x16x32_f16(ph, vh, oacc[j], 0, 0, 0);
                oacc[j] = __builtin_amdgcn_mfma_f32_16x16x32_f16(pl, vh, oacc[j], 0, 0, 0);
                oacc[j] = __builtin_amdgcn_mfma_f32_16x16x32_f16(ph, vl, oacc[j], 0, 0, 0);
            }
        }
    }
#pragma unroll
    for (int r = 0; r < 4; r++) {
        int row = w * 16 + kg * 4 + r;
        int tok = tok0 + row;
        if (tok >= NT) continue;
        float inv = 1.0f / l_[r];
#pragma unroll
        for (int j = 0; j < 4; j++)
            attn_out[((size_t)b * NT + tok) * DIM + hh * DH + j * 16 + mrow] = oacc[j][r] * inv;
    }
}

// attn3: softmax(ql @ k^T) @ v with split-K over NP -> part + ml.  grid (KS3, LM/64, BH)
__global__ __launch_bounds__(256, 2) void k_attn3_mfma(
        const unsigned short* __restrict__ qlh, const unsigned short* __restrict__ qll,
        const unsigned short* __restrict__ kh, const unsigned short* __restrict__ kl_,
        const unsigned short* __restrict__ vth, const unsigned short* __restrict__ vtl,
        float* __restrict__ part, float* __restrict__ ml) {
    int ks = blockIdx.x, rt = blockIdx.y, bh = blockIdx.z;
    int r0 = rt * 64;
    __shared__ __align__(16) unsigned short lQh[4096], lQl[4096];
    __shared__ __align__(16) unsigned short lBh[4096], lBl[4096];
    __shared__ __align__(16) unsigned short lPh[4096], lPl[4096];
    __shared__ __align__(16) unsigned short lVh[4096], lVl[4096];
    int tid = threadIdx.x;
    int lane = tid & 63, w = tid >> 6;
    int mrow = lane & 15, kg = lane >> 4;
    int arow = tid >> 2, acol = (tid & 3) * 8;
    {   // stage ql tile once
        size_t src = ((size_t)bh * LM + r0 + arow) * DH + acol;
        async16(qlh + src,      lQh + tid * 8);
        async16(qlh + src + 32, lQh + 2048 + tid * 8);
        async16(qll + src,      lQl + tid * 8);
        async16(qll + src + 32, lQl + 2048 + tid * 8);
    }
    float m_[4], l_[4];
    f32x4_t oacc[4];
#pragma unroll
    for (int r = 0; r < 4; r++) { m_[r] = -1e30f; l_[r] = 0.f; }
#pragma unroll
    for (int j = 0; j < 4; j++) oacc[j] = (f32x4_t){0.f, 0.f, 0.f, 0.f};
    for (int t0 = ks * KC3; t0 < (ks + 1) * KC3; t0 += 64) {
        if (t0 != ks * KC3) __syncthreads();
        {
            size_t sb = ((size_t)bh * NP + t0 + arow) * DH + acol;
            async16(kh + sb,       lBh + tid * 8);
            async16(kh + sb + 32,  lBh + 2048 + tid * 8);
            async16(kl_ + sb,      lBl + tid * 8);
            async16(kl_ + sb + 32, lBl + 2048 + tid * 8);
            size_t sv = ((size_t)bh * DH + arow) * NP + t0 + acol;
            async16(vth + sv,      lVh + tid * 8);
            async16(vth + sv + 32, lVh + 2048 + tid * 8);
            async16(vtl + sv,      lVl + tid * 8);
            async16(vtl + sv + 32, lVl + 2048 + tid * 8);
        }
        __syncthreads();
        f32x4_t acc1[4];
#pragma unroll
        for (int j = 0; j < 4; j++) acc1[j] = (f32x4_t){0.f, 0.f, 0.f, 0.f};
#pragma unroll
        for (int s = 0; s < 2; s++) {
            int ao = (s * 64 + w * 16 + mrow) * 32 + kg * 8;
            f16x8_t ah = *(const f16x8_t*)(lQh + ao);
            f16x8_t al = *(const f16x8_t*)(lQl + ao);
#pragma unroll
            for (int j = 0; j < 4; j++) {
                int bo = (s * 64 + j * 16 + mrow) * 32 + kg * 8;
                f16x8_t bhv = *(const f16x8_t*)(lBh + bo);
                f16x8_t blv = *(const f16x8_t*)(lBl + bo);
                acc1[j] = __builtin_amdgcn_mfma_f32_16x16x32_f16(ah, bhv, acc1[j], 0, 0, 0);
                acc1[j] = __builtin_amdgcn_mfma_f32_16x16x32_f16(al, bhv, acc1[j], 0, 0, 0);
                acc1[j] = __builtin_amdgcn_mfma_f32_16x16x32_f16(ah, blv, acc1[j], 0, 0, 0);
            }
        }
#pragma unroll
        for (int r = 0; r < 4; r++) {
            float cm = fmaxf(fmaxf(acc1[0][r], acc1[1][r]), fmaxf(acc1[2][r], acc1[3][r]));
            cm = fmaxf(cm, __shfl_xor(cm, 1));
            cm = fmaxf(cm, __shfl_xor(cm, 2));
            cm = fmaxf(cm, __shfl_xor(cm, 4));
            cm = fmaxf(cm, __shfl_xor(cm, 8));
            float mn = fmaxf(m_[r], cm);
            float f = __expf(m_[r] - mn);
            float p0 = __expf(acc1[0][r] - mn);
            float p1 = __expf(acc1[1][r] - mn);
            float p2 = __expf(acc1[2][r] - mn);
            float p3 = __expf(acc1[3][r] - mn);
            float ps = p0 + p1 + p2 + p3;
            ps += __shfl_xor(ps, 1);
            ps += __shfl_xor(ps, 2);
            ps += __shfl_xor(ps, 4);
            ps += __shfl_xor(ps, 8);
            l_[r] = l_[r] * f + ps;
            m_[r] = mn;
#pragma unroll
            for (int j = 0; j < 4; j++) oacc[j][r] *= f;
            int row = w * 16 + kg * 4 + r;
            float pv[4] = {p0, p1, p2, p3};
#pragma unroll
            for (int j = 0; j < 4; j++) {
                unsigned short ph_, pl_;
                split2(pv[j], ph_, pl_);
                int col = j * 16 + mrow;
                int off = ((col >> 5) * 64 + row) * 32 + (col & 31);
                lPh[off] = ph_; lPl[off] = pl_;
            }
        }
        __syncthreads();
#pragma unroll
        for (int s = 0; s < 2; s++) {
            int ao = (s * 64 + w * 16 + mrow) * 32 + kg * 8;
            f16x8_t ph = *(const f16x8_t*)(lPh + ao);
            f16x8_t pl = *(const f16x8_t*)(lPl + ao);
#pragma unroll
            for (int j = 0; j < 4; j++) {
                int bo = (s * 64 + j * 16 + mrow) * 32 + kg * 8;
                f16x8_t vh = *(const f16x8_t*)(lVh + bo);
                f16x8_t vl = *(const f16x8_t*)(lVl + bo);
                oacc[j] = __builtin_amdgcn_mfma_f32_16x16x32_f16(ph, vh, oacc[j], 0, 0, 0);
                oacc[j] = __builtin_amdgcn_mfma_f32_16x16x32_f16(pl, vh, oacc[j], 0, 0, 0);
                oacc[j] = __builtin_amdgcn_mfma_f32_16x16x32_f16(ph, vl, oacc[j], 0, 0, 0);
            }
        }
    }
#pragma unroll
    for (int r = 0; r < 4; r++) {
        int rg = r0 + w * 16 + kg * 4 + r;
        size_t base = (size_t)(bh * KS3 + ks) * LM + rg;
        if (mrow == 0) {
            ml[base * 2 + 0] = m_[r];
            ml[base * 2 + 1] = l_[r];
        }
#pragma unroll
        for (int j = 0; j < 4; j++)
            part[base * DH + j * 16 + mrow] = oacc[j][r];
    }
}

// combine split-K partials with m/l rescale; writes normalized a3v (fp32)
__global__ void k_attn3_reduce(const float* __restrict__ part, const float* __restrict__ ml,
                               float* __restrict__ a3v) {
    int idx = blockIdx.x * 256 + threadIdx.x;
    if (idx >= BH * LM * DH) return;
    int d = idx & 63;
    int r = (idx >> 6) & (LM - 1);
    int bh = idx >> 14;
    float M = -1e30f;
    for (int ks = 0; ks < KS3; ks++)
        M = fmaxf(M, ml[((size_t)(bh * KS3 + ks) * LM + r) * 2]);
    float L = 0.f, s = 0.f;
    for (int ks = 0; ks < KS3; ks++) {
        size_t base = (size_t)(bh * KS3 + ks) * LM + r;
        float f = __expf(ml[base * 2] - M);
        L += ml[base * 2 + 1] * f;
        s += part[base * DH + d] * f;
    }
    a3v[((size_t)bh * LM + r) * DH + d] = s / L;
}

// ---------------- FUSED residual conv + split: actb = split(attn_out + conv33(V)) ----------------
// grid (ceil(NT/64), BH). Stages V[96][64] in LDS once per 64-token tile.
__global__ __launch_bounds__(256) void k_res_split(
        const float* __restrict__ V, const float* __restrict__ rk,
        const float* __restrict__ attn_out,
        unsigned short* __restrict__ yh, unsigned short* __restrict__ yl) {
    int tt = blockIdx.x, bh = blockIdx.y;
    int b = bh / NHEADS, hh = bh % NHEADS;
    int tok0 = tt * 64;
    __shared__ float Vs[96][64];
    __shared__ float k33[33];
    int tid = threadIdx.x;
    if (tid < 33) k33[tid] = rk[hh * 33 + tid];
    // stage V rows [tok0+PADT-16, tok0+PADT+80) — 96 rows x 64 cols
    int g0 = tok0 + PADT - 16;
#pragma unroll
    for (int u = 0; u < 6; u++) {
        int idx = tid + u * 256;           // 0..1535 float4 slots
        int row = idx >> 4, c4 = (idx & 15) * 4;
        int g = g0 + row;
        float4 v = make_float4(0.f, 0.f, 0.f, 0.f);
        if (g < NP) v = *(const float4*)(V + ((size_t)bh * NP + g) * DH + c4);
        *(float4*)&Vs[row][c4] = v;
    }
    __syncthreads();
    int d = tid & 63, wq = tid >> 6;
#pragma unroll
    for (int i = 0; i < 16; i++) {
        int lt = wq + i * 4;               // local token 0..63
        int tok = tok0 + lt;
        if (tok >= NT) continue;
        float s = 0.f;
#pragma unroll
        for (int u = 0; u < 33; u++) s += Vs[lt + u][d] * k33[u];
        size_t row = (size_t)b * NT + tok;
        float v = attn_out[row * DIM + hh * DH + d] + s;
        unsigned short h, l; split2(v, h, l);
        yh[row * DIM + hh * DH + d] = h;
        yl[row * DIM + hh * DH + d] = l;
    }
}

// ---------------- PPEG ----------------
__global__ void k_combine(const float* __restrict__ k7, const float* __restrict__ b7,
                          const float* __restrict__ k5, const float* __restrict__ b5,
                          const float* __restrict__ k3, const float* __restrict__ b3,
                          float* __restrict__ Kc, float* __restrict__ biasC) {
    int tap = blockIdx.y;
    int c = blockIdx.x * 256 + threadIdx.x;
    if (c >= DIM) return;
    int dy = tap / 7 - 3, dx = tap % 7 - 3;
    int ady = dy < 0 ? -dy : dy, adx = dx < 0 ? -dx : dx;
    float w = k7[(size_t)c * 49 + tap];
    if (ady <= 2 && adx <= 2) w += k5[(size_t)c * 25 + (dy + 2) * 5 + (dx + 2)];
    if (ady <= 1 && adx <= 1) w += k3[(size_t)c * 9 + (dy + 1) * 3 + (dx + 1)];
    if (dy == 0 && dx == 0) w += 1.0f;
    Kc[(size_t)tap * DIM + c] = w;
    if (tap == 0) biasC[c] = b7[c] + b5[c] + b3[c];
}

// LDS-tiled PPEG: 32x32 pixel tile, 8-channel group, halo 3
#define PT 32
#define PH 38
__global__ __launch_bounds__(256) void k_ppeg2(
        const float* __restrict__ h1, const float* __restrict__ Kc,
        const float* __restrict__ biasC, float* __restrict__ h2) {
    int xt = blockIdx.x, yt = blockIdx.y;
    int bz = blockIdx.z;
    int b = bz >> 6, cg = bz & 63, c0 = cg * 8;
    __shared__ __align__(16) float sin2[PH * PH * 8];
    __shared__ __align__(16) float wk2[49 * 8];
    __shared__ float sb[8];
    int tid = threadIdx.x;
    for (int i2 = tid; i2 < 392; i2 += 256) {
        int tap = i2 >> 3, ch = i2 & 7;
        wk2[tap * 8 + ch] = Kc[(size_t)tap * DIM + c0 + ch];
    }
    if (tid < 8) sb[tid] = biasC[c0 + tid];
    for (int p = tid; p < PH * PH; p += 256) {
        int ly = p / PH, lx = p % PH;
        int gy = yt * PT + ly - 3, gx = xt * PT + lx - 3;
        float4 v0 = make_float4(0.f, 0.f, 0.f, 0.f), v1 = v0;
        if ((unsigned)gy < 128u && (unsigned)gx < 128u) {
            const float* src = h1 + ((size_t)b * NT + 1 + (size_t)gy * 128 + gx) * DIM + c0;
            v0 = *(const float4*)src;
            v1 = *(const float4*)(src + 4);
        }
        *(float4*)&sin2[p * 8] = v0;
        *(float4*)&sin2[p * 8 + 4] = v1;
    }
    __syncthreads();
    int px = tid & 31, py0 = tid >> 5;
    for (int ry = 0; ry < 4; ry++) {
        int py = py0 + ry * 8;
        float accv[8];
#pragma unroll
        for (int ch = 0; ch < 8; ch++) accv[ch] = sb[ch];
        for (int dy = 0; dy < 7; dy++)
#pragma unroll
            for (int dx = 0; dx < 7; dx++) {
                int pi = (py + dy) * PH + px + dx;
                float4 s0 = *(const float4*)&sin2[pi * 8];
                float4 s1 = *(const float4*)&sin2[pi * 8 + 4];
                int tp = dy * 7 + dx;
                float4 w0 = *(const float4*)&wk2[tp * 8];
                float4 w1 = *(const float4*)&wk2[tp * 8 + 4];
                accv[0] += s0.x * w0.x; accv[1] += s0.y * w0.y;
                accv[2] += s0.z * w0.z; accv[3] += s0.w * w0.w;
                accv[4] += s1.x * w1.x; accv[5] += s1.y * w1.y;
                accv[6] += s1.z * w1.z; accv[7] += s1.w * w1.w;
            }
        float* dst = h2 + ((size_t)b * NT + 1 + (size_t)(yt * PT + py) * 128 + xt * PT + px) * DIM + c0;
        *(float4*)dst = make_float4(accv[0], accv[1], accv[2], accv[3]);
        *(float4*)(dst + 4) = make_float4(accv[4], accv[5], accv[6], accv[7]);
    }
}

// ---------------- cls-only attention tail (attention #2) ----------------
__global__ __launch_bounds__(256) void k_cls_attn(
        const float* __restrict__ q, const float* __restrict__ kl,
        const float* __restrict__ M2, const float* __restrict__ V,
        const float* __restrict__ rk, float* __restrict__ attn_cls) {
    int bh = blockIdx.x;
    int b = bh / NHEADS, hh = bh % NHEADS;
    int tid = threadIdx.x;
    __shared__ float qr[DH];
    __shared__ float sc[LM];
    __shared__ float red[256];
    if (tid < DH) qr[tid] = q[((size_t)bh * NP + PADT) * DH + tid];
    __syncthreads();
    float s = 0.f;
    const float* kp = kl + ((size_t)bh * LM + tid) * DH;
    for (int d2 = 0; d2 < DH; d2++) s += qr[d2] * kp[d2];
    red[tid] = s;
    __syncthreads();
    for (int o = 128; o > 0; o >>= 1) { if (tid < o) red[tid] = fmaxf(red[tid], red[tid + o]); __syncthreads(); }
    float mx = red[0];
    __syncthreads();
    float e = __expf(s - mx);
    red[tid] = e;
    __syncthreads();
    for (int o = 128; o > 0; o >>= 1) { if (tid < o) red[tid] += red[tid + o]; __syncthreads(); }
    float tot = red[0];
    sc[tid] = e / tot;
    __syncthreads();
    if (tid < DH) {
        int d = tid;
        float o1 = 0.f;
        for (int j = 0; j < LM; j++) o1 += sc[j] * M2[((size_t)bh * LM + j) * DH + d];
        float r2 = 0.f;
        for (int u = 0; u < 33; u++) {
            int tp = PADT - 16 + u;
            r2 += V[((size_t)bh * NP + tp) * DH + d] * rk[hh * 33 + u];
        }
        attn_cls[(size_t)b * DIM + hh * DH + d] = o1 + r2;
    }
}

__global__ __launch_bounds__(256) void k_cls_proj(
        const float* __restrict__ attn_cls, const float* __restrict__ Wout,
        const float* __restrict__ bout, const float* __restrict__ h2, float* __restrict__ h_cls) {
    int b = blockIdx.x, tid = threadIdx.x;
    __shared__ float a[DIM];
    a[tid] = attn_cls[(size_t)b * DIM + tid];
    a[tid + 256] = attn_cls[(size_t)b * DIM + tid + 256];
    __syncthreads();
    for (int c = tid; c < DIM; c += 256) {
        float s = bout[c];
        for (int k2 = 0; k2 < DIM; k2++) s += a[k2] * Wout[(size_t)k2 * DIM + c];
        h_cls[(size_t)b * DIM + c] = h2[(size_t)b * NT * DIM + c] + s;
    }
}

__global__ __launch_bounds__(256) void k_final(
        const float* __restrict__ h_cls, const float* __restrict__ g, const float* __restrict__ bb,
        const float* __restrict__ W2, const float* __restrict__ b2, float* __restrict__ out) {
    int b = blockIdx.x, tid = threadIdx.x;
    const float* x = h_cls + (size_t)b * DIM;
    __shared__ float red[256];
    float v0 = x[tid], v1 = x[tid + 256];
    red[tid] = v0 + v1;
    __syncthreads();
    for (int o = 128; o > 0; o >>= 1) { if (tid < o) red[tid] += red[tid + o]; __syncthreads(); }
    float mu = red[0] * (1.0f / DIM);
    __syncthreads();
    float d0 = v0 - mu, d1 = v1 - mu;
    red[tid] = d0 * d0 + d1 * d1;
    __syncthreads();
    for (int o = 128; o > 0; o >>= 1) { if (tid < o) red[tid] += red[tid + o]; __syncthreads(); }
    float rs = rsqrtf(red[0] * (1.0f / DIM) + LNEPS);
    float y0 = d0 * rs * g[tid] + bb[tid];
    float y1 = d1 * rs * g[tid + 256] + bb[tid + 256];
    red[tid] = y0 * W2[tid] + y1 * W2[tid + 256];
    __syncthreads();
    for (int o = 128; o > 0; o >>= 1) { if (tid < o) red[tid] += red[tid + o]; __syncthreads(); }
    if (tid == 0) out[b] = red[0] + b2[0];
}

// ---------------- host orchestration ----------------
struct AttnBufs {
    float *q, *k, *v, *ql, *kl;
    float *a2, *za, *zb, *xz, *ta, *tb;
    float *S, *part, *ml, *a3v, *M2, *scal;
    float *attn_cls, *h_cls;
    unsigned short *actb_h, *actb_l;
};

static void run_attention(hipStream_t stream, const float* hin, float* h_residual,
                          float* attn_out,
                          const float* lng, const float* lnb,
                          const unsigned short* Wqkvt_h, const unsigned short* Wqkvt_l,
                          const unsigned short* Woutt_h, const unsigned short* Woutt_l,
                          const float* Wout_f32, const float* bout,
                          const float* resk, bool full, const AttnBufs& B_) {
    // split-fp16 operand buffers carved from S (dead outside w1 staging; ~208 MB << 272 MB)
    unsigned short* sp = (unsigned short*)B_.S;
    auto su = [&](size_t n) { unsigned short* p = sp; sp += (n + 63) & ~(size_t)63; return p; };
    const size_t NQ = (size_t)BH * NP * DH;
    const size_t NL = (size_t)BH * LM * DH;
    unsigned short *qsh = su(NQ), *qsl = su(NQ);
    unsigned short *ksh = su(NQ), *ksl = su(NQ);
    unsigned short *vth = su(NQ), *vtl = su(NQ);
    unsigned short *qlsh = su(NL), *qlsl = su(NL);
    unsigned short *klsh = su(NL), *klsl = su(NL);
    unsigned short *m2th = su(NL), *m2tl = su(NL);

    k_ln_split<<<dim3(BATCH * NT), 256, 0, stream>>>(hin, lng, lnb, B_.actb_h, B_.actb_l);
    k_zero_pads<<<dim3((BH * PADT * DH + 255) / 256), 256, 0, stream>>>(B_.q, B_.k, B_.v);
    // qkv GEMM, XCD-chunked swizzled 1-D grid
    k_qkv_s<<<dim3(3084), 256, 0, stream>>>(B_.actb_h, B_.actb_l, Wqkvt_h, Wqkvt_l, B_.q, B_.k, B_.v);
    // split-fp16 prep for MFMA attention
    const int NQ4 = BH * NP * DH / 4;
    if (full)
        k_cvt_split<<<dim3((NQ4 + 255) / 256), 256, 0, stream>>>(B_.q, qsh, qsl, NQ4);
    k_cvt_split<<<dim3((NQ4 + 255) / 256), 256, 0, stream>>>(B_.k, ksh, ksl, NQ4);
    k_vt_split<<<dim3(NP / 64, BH), 256, 0, stream>>>(B_.v, vth, vtl);
    k_landmark<<<dim3(1, LM, BH), 64, 0, stream>>>(B_.q, B_.ql, qlsh, qlsl);
    k_landmark<<<dim3(1, LM, BH), 64, 0, stream>>>(B_.k, B_.kl, klsh, klsl);
    k_scores<<<dim3(LM / 64, LM / 64, BH), 256, 0, stream>>>(B_.ql, B_.kl, B_.a2, LM, LM);
    k_softmax<<<dim3(BH * LM), 256, 0, stream>>>(B_.a2, LM);
    hipMemsetAsync(B_.scal, 0, 2 * sizeof(float), stream);
    k_pinv_scal<<<dim3(BH), 256, 0, stream>>>(B_.a2, B_.scal);
    k_z0<<<dim3(1, LM, BH), 256, 0, stream>>>(B_.a2, B_.scal, B_.za);
    float* zc = B_.za; float* zn = B_.zb;
    // Newton-Schulz, diag_sub fused into GEMM epilogue
    for (int it = 0; it < 6; it++) {
        k_gemm_b64<<<dim3(4, 4, BH), 256, 0, stream>>>(B_.a2, zc, B_.xz, nullptr, LM, LM, LM, 1.f, 0.f, 0.f);
        k_gemm_b64<<<dim3(4, 4, BH), 256, 0, stream>>>(B_.xz, B_.xz, B_.tb, B_.xz, LM, LM, LM, 1.f, -7.f, 15.f);
        k_gemm_b64<<<dim3(4, 4, BH), 256, 0, stream>>>(B_.xz, B_.tb, B_.ta, nullptr, LM, LM, LM, -1.f, 0.f, 13.f);
        k_gemm_b64<<<dim3(4, 4, BH), 256, 0, stream>>>(zc, B_.ta, zn, nullptr, LM, LM, LM, 0.25f, 0.f, 0.f);
        std::swap(zc, zn);
    }
    // fused attn3 (MFMA): scores + online softmax + P@V (split-K over NP)
    k_attn3_mfma<<<dim3(KS3, LM / 64, BH), 256, 0, stream>>>(qlsh, qlsl, ksh, ksl, vth, vtl, B_.part, B_.ml);
    k_attn3_reduce<<<dim3(BH * LM * DH / 256), 256, 0, stream>>>(B_.part, B_.ml, B_.a3v);
    k_gemm_b64<<<dim3(1, 4, BH), 256, 0, stream>>>(zc, B_.a3v, B_.M2, nullptr, LM, DH, LM, 1.f, 0.f, 0.f);
    if (full) {
        k_m2t_split<<<dim3(LM / 64, BH), 256, 0, stream>>>(B_.M2, m2th, m2tl);
        k_attn1_mfma<<<dim3((NT + 63) / 64, BH), 256, 0, stream>>>(qsh, qsl, klsh, klsl, m2th, m2tl, attn_out);
        // fused: conv(V) + attn_out -> split fp16 actb
        k_res_split<<<dim3((NT + 63) / 64, BH), 256, 0, stream>>>(B_.v, resk, attn_out, B_.actb_h, B_.actb_l);
        k_outproj_s<<<dim3(1028), 256, 0, stream>>>(B_.actb_h, B_.actb_l, Woutt_h, Woutt_l, bout, h_residual);
    } else {
        k_cls_attn<<<dim3(BH), 256, 0, stream>>>(B_.q, B_.kl, B_.M2, B_.v, resk, B_.attn_cls);
        k_cls_proj<<<dim3(BATCH), 256, 0, stream>>>(B_.attn_cls, Wout_f32, bout, hin, B_.h_cls);
    }
}

extern "C" void kernel_launch(void* const* d_in, const int* in_sizes, int n_in,
                              void* d_out, int out_size, void* d_ws, size_t ws_size,
                              hipStream_t stream) {
    const float* features = (const float*)d_in[0];
    const float* W1    = (const float*)d_in[1];
    const float* b1    = (const float*)d_in[2];
    const float* cls   = (const float*)d_in[3];
    const float* ln1_g = (const float*)d_in[4];
    const float* ln1_b = (const float*)d_in[5];
    const float* Wqkv1 = (const float*)d_in[6];
    const float* Wout1 = (const float*)d_in[7];
    const float* bout1 = (const float*)d_in[8];
    const float* resk1 = (const float*)d_in[9];
    const float* ln2_g = (const float*)d_in[10];
    const float* ln2_b = (const float*)d_in[11];
    const float* Wqkv2 = (const float*)d_in[12];
    const float* Wout2 = (const float*)d_in[13];
    const float* bout2 = (const float*)d_in[14];
    const float* resk2 = (const float*)d_in[15];
    const float* k7    = (const float*)d_in[16];
    const float* b7c   = (const float*)d_in[17];
    const float* k5    = (const float*)d_in[18];
    const float* b5c   = (const float*)d_in[19];
    const float* k3    = (const float*)d_in[20];
    const float* b3c   = (const float*)d_in[21];
    const float* lnf_g = (const float*)d_in[22];
    const float* lnf_b = (const float*)d_in[23];
    const float* W2    = (const float*)d_in[24];
    const float* b2    = (const float*)d_in[25];
    float* out = (float*)d_out;

    float* ws = (float*)d_ws;
    size_t off = 0;
    auto alloc = [&](size_t n) { float* p = ws + off; off += (n + 63) & ~(size_t)63; return p; };
    float* h1  = alloc((size_t)BATCH * NT * DIM);
    float* h2  = alloc((size_t)BATCH * NT * DIM);   // also attn_out of layer 1
    AttnBufs Bu;
    Bu.q    = alloc((size_t)BH * NP * DH);
    Bu.k    = alloc((size_t)BH * NP * DH);
    Bu.v    = alloc((size_t)BH * NP * DH);
    Bu.S    = alloc((size_t)BH * NP * LM);          // aliased: feat hi/lo (f16), attn split bufs
    Bu.ql   = alloc((size_t)BH * LM * DH);
    Bu.kl   = alloc((size_t)BH * LM * DH);
    Bu.a2   = alloc((size_t)BH * LM * LM);
    Bu.za   = alloc((size_t)BH * LM * LM);
    Bu.zb   = alloc((size_t)BH * LM * LM);
    Bu.xz   = alloc((size_t)BH * LM * LM);
    Bu.ta   = alloc((size_t)BH * LM * LM);
    Bu.tb   = alloc((size_t)BH * LM * LM);
    Bu.part = alloc((size_t)BH * KS3 * LM * DH);
    Bu.ml   = alloc((size_t)BH * KS3 * LM * 2);
    Bu.a3v  = alloc((size_t)BH * LM * DH);
    Bu.M2   = alloc((size_t)BH * LM * DH);
    Bu.scal = alloc(64);
    Bu.attn_cls = alloc(BATCH * DIM);
    Bu.h_cls    = alloc(BATCH * DIM);
    float* Kc    = alloc(49 * DIM);
    float* biasC = alloc(DIM);
    Bu.actb_h = (unsigned short*)alloc((size_t)MPAD * DIM / 2);
    Bu.actb_l = (unsigned short*)alloc((size_t)MPAD * DIM / 2);
    unsigned short* W1t_h   = (unsigned short*)alloc((size_t)DIM * INDIM / 2);
    unsigned short* W1t_l   = (unsigned short*)alloc((size_t)DIM * INDIM / 2);
    unsigned short* Wqkvt_h = (unsigned short*)alloc((size_t)DIM * 3 * DIM / 2);  // shared by both layers
    unsigned short* Wqkvt_l = (unsigned short*)alloc((size_t)DIM * 3 * DIM / 2);
    unsigned short* Wo1t_h  = (unsigned short*)alloc((size_t)DIM * DIM / 2);
    unsigned short* Wo1t_l  = (unsigned short*)alloc((size_t)DIM * DIM / 2);
    // feat hi/lo alias into S (S unused until after w1 GEMM)
    unsigned short* featb_h = (unsigned short*)Bu.S;
    unsigned short* featb_l = featb_h + (size_t)BATCH * 16384 * INDIM;

    // zero pad rows of activation buffers (rows MROWS..MPAD), once per launch
    hipMemsetAsync(Bu.actb_h + (size_t)MROWS * DIM, 0, (size_t)(MPAD - MROWS) * DIM * 2, stream);
    hipMemsetAsync(Bu.actb_l + (size_t)MROWS * DIM, 0, (size_t)(MPAD - MROWS) * DIM * 2, stream);

    // weight prep (split f16, transposed to [N][K])
    k_wt_split<<<dim3((INDIM * DIM + 255) / 256), 256, 0, stream>>>(W1, W1t_h, W1t_l, INDIM, DIM);
    k_wt_split<<<dim3((DIM * 3 * DIM + 255) / 256), 256, 0, stream>>>(Wqkv1, Wqkvt_h, Wqkvt_l, DIM, 3 * DIM);
    k_wt_split<<<dim3((DIM * DIM + 255) / 256), 256, 0, stream>>>(Wout1, Wo1t_h, Wo1t_l, DIM, DIM);
    // features -> split f16
    k_cvt_split<<<dim3((BATCH * 16384 * INDIM / 4 + 255) / 256), 256, 0, stream>>>(
        features, featb_h, featb_l, BATCH * 16384 * INDIM / 4);

    // 1) h = relu(features @ W1 + b1), prepend cls   (XCD-swizzled 1-D grid)
    k_set_cls<<<dim3(4), 256, 0, stream>>>(cls, h1);
    k_w1_s<<<dim3(1024), 256, 0, stream>>>(featb_h, featb_l, W1t_h, W1t_l, b1, h1);
    // 2) h += nystrom_attention(LN(h))  (full)
    run_attention(stream, h1, h1, h2, ln1_g, ln1_b, Wqkvt_h, Wqkvt_l, Wo1t_h, Wo1t_l,
                  nullptr, bout1, resk1, true, Bu);
    // 3) PPEG
    k_combine<<<dim3(2, 49), 256, 0, stream>>>(k7, b7c, k5, b5c, k3, b3c, Kc, biasC);
    k_ppeg2<<<dim3(4, 4, BATCH * 64), 256, 0, stream>>>(h1, Kc, biasC, h2);
    k_copy_cls<<<dim3(4), 256, 0, stream>>>(h1, h2);
    // 4) second attention — only cls token needed downstream; reuse Wqkv staging buffer
    k_wt_split<<<dim3((DIM * 3 * DIM + 255) / 256), 256, 0, stream>>>(Wqkv2, Wqkvt_h, Wqkvt_l, DIM, 3 * DIM);
    run_attention(stream, h2, nullptr, nullptr, ln2_g, ln2_b, Wqkvt_h, Wqkvt_l, nullptr, nullptr,
                  Wout2, bout2, resk2, false, Bu);
    // 5) final LN on cls + linear head
    k_final<<<dim3(BATCH), 256, 0, stream>>>(Bu.h_cls, lnf_g, lnf_b, W2, b2, out);
}